// Round 2
// baseline (4422.683 us; speedup 1.0000x reference)
//
#include <hip/hip_runtime.h>
#include <stdint.h>

// GraphPropLayer on MI355X — round 2: fp16 table fallback (was bf16), fp16 ghs,
// precise tanh. Structure unchanged from round 1.
//
// agg = segsum_t(relu(Pfa[f]+Pfb[t]+bf1) @ Wf2.T + bf2) + segsum_f(... rev ...)
// gi  = agg @ W_ih.T + b_ih
//     = S_f @ (W_ih@Wf2).T + S_r @ (W_ih@Wr2).T + indeg*(W_ih@bf2) + outdeg*(W_ih@br2) + b_ih
// where S_f[n] = sum_{e: t=n} relu(pre_fwd), S_r[n] = sum_{e: f=n} relu(pre_rev).
// Pipeline: prep weights -> K1 projections (T table) -> K2 edge gather/relu/scatter -> K3 GRU.

#define NN 50000
#define NE 512000

typedef unsigned short u16;
typedef unsigned int u32;

__device__ __forceinline__ float h2f(u16 u) {
  _Float16 h;
  __builtin_memcpy(&h, &u, 2);
  return (float)h;
}
__device__ __forceinline__ u16 f2h(float f) {
  _Float16 h = (_Float16)f;
  u16 u;
  __builtin_memcpy(&u, &h, 2);
  return u;
}

__device__ __forceinline__ void store8v(float* p, const float* v) {
  *(float4*)p       = make_float4(v[0], v[1], v[2], v[3]);
  *(float4*)(p + 4) = make_float4(v[4], v[5], v[6], v[7]);
}
__device__ __forceinline__ void store8v(u16* p, const float* v) {
  u16 t[8];
#pragma unroll
  for (int j = 0; j < 8; ++j) t[j] = f2h(v[j]);
  *(uint4*)p = *(const uint4*)t;
}
__device__ __forceinline__ float4 load4v(const float* p) { return *(const float4*)p; }
__device__ __forceinline__ float4 load4v(const u16* p) {
  ushort4 u = *(const ushort4*)p;
  return make_float4(h2f(u.x), h2f(u.y), h2f(u.z), h2f(u.w));
}

// ---------------- prep kernels (tiny) ----------------

// Wcat[1024][128]: packed layer-1 weight columns for the T-table GEMM.
// c<256: Wf1[c][0:128] (+bf1) | 256..511: Wr1[c-256][128:256] | 512..767: Wf1[c-512][128:256]
// | 768..1023: Wr1[c-768][0:128] (+br1)
__global__ void k_wcat(const float* __restrict__ Wf1, const float* __restrict__ bf1,
                       const float* __restrict__ Wr1, const float* __restrict__ br1,
                       float* __restrict__ Wcat, float* __restrict__ biascat) {
  int c = blockIdx.x;
  int k = threadIdx.x;
  const float* src;
  if (c < 256)      src = Wf1 + (size_t)c * 256;
  else if (c < 512) src = Wr1 + (size_t)(c - 256) * 256 + 128;
  else if (c < 768) src = Wf1 + (size_t)(c - 512) * 256 + 128;
  else              src = Wr1 + (size_t)(c - 768) * 256;
  Wcat[(size_t)c * 128 + k] = src[k];
  if (k == 0) biascat[c] = (c < 256) ? bf1[c] : ((c >= 768) ? br1[c - 768] : 0.f);
}

// Gcat[384][512] = [W_ih@Wf2 | W_ih@Wr2]  (k-contiguous rows)
__global__ void k_gcat(const float* __restrict__ W_ih, const float* __restrict__ Wf2,
                       const float* __restrict__ Wr2, float* __restrict__ Gcat) {
  int b = blockIdx.x;
  int c = b % 384, w = b / 384;
  const float* W2 = w ? Wr2 : Wf2;
  int k = threadIdx.x;  // 0..255, coalesced over W2 columns
  float acc = 0.f;
  for (int o = 0; o < 256; ++o)
    acc = fmaf(W_ih[(size_t)c * 256 + o], W2[(size_t)o * 256 + k], acc);
  Gcat[(size_t)c * 512 + (size_t)w * 256 + k] = acc;
}

// vf = W_ih @ bf2, vr = W_ih @ br2 (per-node deg-scaled bias terms)
__global__ void k_vbias(const float* __restrict__ W_ih, const float* __restrict__ bf2,
                        const float* __restrict__ br2, float* __restrict__ vf,
                        float* __restrict__ vr) {
  int c = blockIdx.x * blockDim.x + threadIdx.x;
  if (c >= 384) return;
  float a = 0.f, b = 0.f;
  for (int o = 0; o < 256; ++o) {
    float w = W_ih[(size_t)c * 256 + o];
    a = fmaf(w, bf2[o], a);
    b = fmaf(w, br2[o], b);
  }
  vf[c] = a; vr[c] = b;
}

// ---------------- K1: projection table T[n][1024] = ns[n] @ Wcat.T + biascat ----------------
// BM=64, BN=128, K=128, 256 threads, 4x8 acc/thread.
template <typename TT>
__global__ __launch_bounds__(256) void k_proj(const float* __restrict__ ns,
                                              const float* __restrict__ Wcat,
                                              const float* __restrict__ biascat,
                                              TT* __restrict__ T) {
  __shared__ float As[16][64];
  __shared__ float Bs[16][132];
  const int m0 = blockIdx.x * 64;
  const int c0 = blockIdx.y * 128;
  const int tid = threadIdx.x;
  const int tm = tid >> 4, tn = tid & 15;
  const int ar = tid >> 2, aq = tid & 3;
  float acc[4][8];
#pragma unroll
  for (int i = 0; i < 4; ++i)
#pragma unroll
    for (int j = 0; j < 8; ++j) acc[i][j] = 0.f;

  for (int kt = 0; kt < 8; ++kt) {
    const int k0 = kt * 16;
    __syncthreads();
    {
      int row = m0 + ar;
      float4 v = make_float4(0.f, 0.f, 0.f, 0.f);
      if (row < NN) v = *(const float4*)(ns + (size_t)row * 128 + k0 + aq * 4);
      As[aq * 4 + 0][ar] = v.x; As[aq * 4 + 1][ar] = v.y;
      As[aq * 4 + 2][ar] = v.z; As[aq * 4 + 3][ar] = v.w;
    }
#pragma unroll
    for (int s = 0; s < 2; ++s) {
      int idx = tid + s * 256;
      int ci = idx >> 2, q = idx & 3;
      float4 v = *(const float4*)(Wcat + (size_t)(c0 + ci) * 128 + k0 + q * 4);
      Bs[q * 4 + 0][ci] = v.x; Bs[q * 4 + 1][ci] = v.y;
      Bs[q * 4 + 2][ci] = v.z; Bs[q * 4 + 3][ci] = v.w;
    }
    __syncthreads();
#pragma unroll
    for (int kk = 0; kk < 16; ++kk) {
      float4 a  = *(const float4*)&As[kk][tm * 4];
      float4 b0 = *(const float4*)&Bs[kk][tn * 8];
      float4 b1 = *(const float4*)&Bs[kk][tn * 8 + 4];
      float av[4] = {a.x, a.y, a.z, a.w};
      float bv[8] = {b0.x, b0.y, b0.z, b0.w, b1.x, b1.y, b1.z, b1.w};
#pragma unroll
      for (int i = 0; i < 4; ++i)
#pragma unroll
        for (int j = 0; j < 8; ++j) acc[i][j] = fmaf(av[i], bv[j], acc[i][j]);
    }
  }
  float bias[8];
#pragma unroll
  for (int j = 0; j < 8; ++j) bias[j] = biascat[c0 + tn * 8 + j];
#pragma unroll
  for (int i = 0; i < 4; ++i) {
    int row = m0 + tm * 4 + i;
    if (row < NN) {
      float v[8];
#pragma unroll
      for (int j = 0; j < 8; ++j) v[j] = acc[i][j] + bias[j];
      store8v(T + (size_t)row * 1024 + c0 + tn * 8, v);
    }
  }
}

// ---------------- K2: edge gather + relu + scatter-add ----------------
// For edge e (f,t), uniform j in [0,512): v = relu(T[f][j] + T[t][512+j]);
// j<256 -> S[t][j] (fwd), j>=256 -> S[f][j] (rev). 16 lanes per edge.
template <typename TT>
__global__ __launch_bounds__(256) void k_edge(const int* __restrict__ from,
                                              const int* __restrict__ to,
                                              const TT* __restrict__ T, float* __restrict__ S,
                                              float* __restrict__ indeg,
                                              float* __restrict__ outdeg) {
  const int lane = threadIdx.x & 15;
  const int esub = threadIdx.x >> 4;
  for (int e0 = blockIdx.x * 16; e0 < NE; e0 += gridDim.x * 16) {
    int e = e0 + esub;
    if (e < NE) {
      int f = from[e], t = to[e];
      if (lane == 0) {
        atomicAdd(indeg + t, 1.f);
        atomicAdd(outdeg + f, 1.f);
      }
      const TT* xf = T + (size_t)f * 1024;
      const TT* yt = T + (size_t)t * 1024 + 512;
      float* St = S + (size_t)t * 512;
      float* Sf = S + (size_t)f * 512;
#pragma unroll
      for (int i = 0; i < 8; ++i) {
        int j = i * 64 + lane * 4;
        float4 a = load4v(xf + j);
        float4 b = load4v(yt + j);
        float4 v;
        v.x = fmaxf(a.x + b.x, 0.f);
        v.y = fmaxf(a.y + b.y, 0.f);
        v.z = fmaxf(a.z + b.z, 0.f);
        v.w = fmaxf(a.w + b.w, 0.f);
        float* dst = (i < 4 ? St : Sf) + j;
        atomicAdd(dst + 0, v.x);
        atomicAdd(dst + 1, v.y);
        atomicAdd(dst + 2, v.z);
        atomicAdd(dst + 3, v.w);
      }
    }
  }
}

// ---------------- K3: fused GRU ----------------
// Step A: gh[64][384] = ns_tile @ W_hh.T + b_hh -> fp16 LDS (each thread re-reads only its own)
// Step B: gi[64][384] = S_tile[512] @ Gcat.T (accumulators in regs)
// Epilogue: gates + output, deg-scaled bias terms.
__global__ __launch_bounds__(256) void k_gru(const float* __restrict__ S,
                                             const float* __restrict__ ns,
                                             const float* __restrict__ Gcat,
                                             const float* __restrict__ W_hh,
                                             const float* __restrict__ b_ih,
                                             const float* __restrict__ b_hh,
                                             const float* __restrict__ vf,
                                             const float* __restrict__ vr,
                                             const float* __restrict__ indeg,
                                             const float* __restrict__ outdeg,
                                             float* __restrict__ out) {
  __shared__ float As[16][64];
  __shared__ float Bs[16][388];
  __shared__ u16 ghs[64][384];
  const int m0 = blockIdx.x * 64;
  const int tid = threadIdx.x;
  const int tm = tid >> 4, tn = tid & 15;
  const int ar = tid >> 2, aq = tid & 3;
  float acc[4][24];

  // ---- step A: gh ----
#pragma unroll
  for (int i = 0; i < 4; ++i)
#pragma unroll
    for (int j = 0; j < 24; ++j) acc[i][j] = 0.f;

  for (int kt = 0; kt < 8; ++kt) {
    const int k0 = kt * 16;
    __syncthreads();
    {
      int row = m0 + ar;
      float4 v = make_float4(0.f, 0.f, 0.f, 0.f);
      if (row < NN) v = *(const float4*)(ns + (size_t)row * 128 + k0 + aq * 4);
      As[aq * 4 + 0][ar] = v.x; As[aq * 4 + 1][ar] = v.y;
      As[aq * 4 + 2][ar] = v.z; As[aq * 4 + 3][ar] = v.w;
    }
#pragma unroll
    for (int s = 0; s < 6; ++s) {
      int idx = tid + s * 256;
      int ci = idx >> 2, q = idx & 3;
      float4 v = *(const float4*)(W_hh + (size_t)ci * 128 + k0 + q * 4);
      Bs[q * 4 + 0][ci] = v.x; Bs[q * 4 + 1][ci] = v.y;
      Bs[q * 4 + 2][ci] = v.z; Bs[q * 4 + 3][ci] = v.w;
    }
    __syncthreads();
#pragma unroll
    for (int kk = 0; kk < 16; ++kk) {
      float4 a = *(const float4*)&As[kk][tm * 4];
      float av[4] = {a.x, a.y, a.z, a.w};
      float bv[24];
#pragma unroll
      for (int nt = 0; nt < 3; ++nt) {
        float4 b0 = *(const float4*)&Bs[kk][nt * 128 + tn * 8];
        float4 b1 = *(const float4*)&Bs[kk][nt * 128 + tn * 8 + 4];
        bv[nt * 8 + 0] = b0.x; bv[nt * 8 + 1] = b0.y; bv[nt * 8 + 2] = b0.z; bv[nt * 8 + 3] = b0.w;
        bv[nt * 8 + 4] = b1.x; bv[nt * 8 + 5] = b1.y; bv[nt * 8 + 6] = b1.z; bv[nt * 8 + 7] = b1.w;
      }
#pragma unroll
      for (int i = 0; i < 4; ++i)
#pragma unroll
        for (int j = 0; j < 24; ++j) acc[i][j] = fmaf(av[i], bv[j], acc[i][j]);
    }
  }
#pragma unroll
  for (int nt = 0; nt < 3; ++nt)
#pragma unroll
    for (int j = 0; j < 8; ++j) {
      int c = nt * 128 + tn * 8 + j;
      float bb = b_hh[c];
#pragma unroll
      for (int i = 0; i < 4; ++i) ghs[tm * 4 + i][c] = f2h(acc[i][nt * 8 + j] + bb);
    }

  // ---- step B: gi ----
#pragma unroll
  for (int i = 0; i < 4; ++i)
#pragma unroll
    for (int j = 0; j < 24; ++j) acc[i][j] = 0.f;

  for (int kt = 0; kt < 32; ++kt) {
    const int k0 = kt * 16;
    __syncthreads();
    {
      int row = m0 + ar;
      float4 v = make_float4(0.f, 0.f, 0.f, 0.f);
      if (row < NN) v = *(const float4*)(S + (size_t)row * 512 + k0 + aq * 4);
      As[aq * 4 + 0][ar] = v.x; As[aq * 4 + 1][ar] = v.y;
      As[aq * 4 + 2][ar] = v.z; As[aq * 4 + 3][ar] = v.w;
    }
#pragma unroll
    for (int s = 0; s < 6; ++s) {
      int idx = tid + s * 256;
      int ci = idx >> 2, q = idx & 3;
      float4 v = *(const float4*)(Gcat + (size_t)ci * 512 + k0 + q * 4);
      Bs[q * 4 + 0][ci] = v.x; Bs[q * 4 + 1][ci] = v.y;
      Bs[q * 4 + 2][ci] = v.z; Bs[q * 4 + 3][ci] = v.w;
    }
    __syncthreads();
#pragma unroll
    for (int kk = 0; kk < 16; ++kk) {
      float4 a = *(const float4*)&As[kk][tm * 4];
      float av[4] = {a.x, a.y, a.z, a.w};
      float bv[24];
#pragma unroll
      for (int nt = 0; nt < 3; ++nt) {
        float4 b0 = *(const float4*)&Bs[kk][nt * 128 + tn * 8];
        float4 b1 = *(const float4*)&Bs[kk][nt * 128 + tn * 8 + 4];
        bv[nt * 8 + 0] = b0.x; bv[nt * 8 + 1] = b0.y; bv[nt * 8 + 2] = b0.z; bv[nt * 8 + 3] = b0.w;
        bv[nt * 8 + 4] = b1.x; bv[nt * 8 + 5] = b1.y; bv[nt * 8 + 6] = b1.z; bv[nt * 8 + 7] = b1.w;
      }
#pragma unroll
      for (int i = 0; i < 4; ++i)
#pragma unroll
        for (int j = 0; j < 24; ++j) acc[i][j] = fmaf(av[i], bv[j], acc[i][j]);
    }
  }

  // ---- epilogue: gates ----
#pragma unroll
  for (int i = 0; i < 4; ++i) {
    int row = m0 + tm * 4 + i;
    if (row >= NN) continue;
    float idg = indeg[row], odg = outdeg[row];
    float ov[8];
#pragma unroll
    for (int j = 0; j < 8; ++j) {
      int d = tn * 8 + j;
      float gi0 = acc[i][j]      + idg * vf[d]       + odg * vr[d]       + b_ih[d];
      float gi1 = acc[i][8 + j]  + idg * vf[128 + d] + odg * vr[128 + d] + b_ih[128 + d];
      float gi2 = acc[i][16 + j] + idg * vf[256 + d] + odg * vr[256 + d] + b_ih[256 + d];
      int r = tm * 4 + i;
      float hr = h2f(ghs[r][d]);
      float hz = h2f(ghs[r][128 + d]);
      float hn = h2f(ghs[r][256 + d]);
      float rg = 1.f / (1.f + __expf(-(gi0 + hr)));
      float zg = 1.f / (1.f + __expf(-(gi1 + hz)));
      float ng = tanhf(gi2 + rg * hn);
      float h = ns[(size_t)row * 128 + d];
      ov[j] = (1.f - zg) * ng + zg * h;
    }
    store8v(out + (size_t)row * 128 + tn * 8, ov);
  }
}

// ---------------- launch ----------------
extern "C" void kernel_launch(void* const* d_in, const int* in_sizes, int n_in,
                              void* d_out, int out_size, void* d_ws, size_t ws_size,
                              hipStream_t stream) {
  const float* ns   = (const float*)d_in[0];
  const int* from   = (const int*)d_in[1];
  const int* to     = (const int*)d_in[2];
  const float* Wf1  = (const float*)d_in[3];
  const float* bf1  = (const float*)d_in[4];
  const float* Wf2  = (const float*)d_in[5];
  const float* bf2  = (const float*)d_in[6];
  const float* Wr1  = (const float*)d_in[7];
  const float* br1  = (const float*)d_in[8];
  const float* Wr2  = (const float*)d_in[9];
  const float* br2  = (const float*)d_in[10];
  const float* W_ih = (const float*)d_in[11];
  const float* W_hh = (const float*)d_in[12];
  const float* b_ih = (const float*)d_in[13];
  const float* b_hh = (const float*)d_in[14];
  float* out = (float*)d_out;

  // workspace layout (256B aligned)
  char* w = (char*)d_ws;
  float* Wcat    = (float*)(w + 0);          // 1024*128*4   = 524288
  float* biascat = (float*)(w + 524288);     // 4096
  float* Gcat    = (float*)(w + 528384);     // 384*512*4    = 786432
  float* vf      = (float*)(w + 1314816);    // 1536
  float* vr      = (float*)(w + 1316352);    // 1536
  float* indeg   = (float*)(w + 1317888);    // 200704
  float* outdeg  = (float*)(w + 1518592);    // 200704
  float* S       = (float*)(w + 1719296);    // 50000*512*4  = 102400000
  void*  Tp      = (void*)(w + 104119296);   // T table: fp32 204800000 or fp16 102400000

  const unsigned long long NEED_F32 = 308919296ull;
  bool t32 = (ws_size >= NEED_F32);

  // zero indeg|outdeg|S in one shot (contiguous)
  hipMemsetAsync(w + 1317888, 0, 200704 * 2 + 102400000, stream);

  k_wcat<<<1024, 128, 0, stream>>>(Wf1, bf1, Wr1, br1, Wcat, biascat);
  k_gcat<<<768, 256, 0, stream>>>(W_ih, Wf2, Wr2, Gcat);
  k_vbias<<<3, 128, 0, stream>>>(W_ih, bf2, br2, vf, vr);

  if (t32) {
    k_proj<float><<<dim3(782, 8), 256, 0, stream>>>(ns, Wcat, biascat, (float*)Tp);
    k_edge<float><<<4096, 256, 0, stream>>>(from, to, (const float*)Tp, S, indeg, outdeg);
  } else {
    k_proj<u16><<<dim3(782, 8), 256, 0, stream>>>(ns, Wcat, biascat, (u16*)Tp);
    k_edge<u16><<<4096, 256, 0, stream>>>(from, to, (const u16*)Tp, S, indeg, outdeg);
  }

  k_gru<<<782, 256, 0, stream>>>(S, ns, Gcat, W_hh, b_ih, b_hh, vf, vr, indeg, outdeg, out);
}

// Round 3
// 1310.688 us; speedup vs baseline: 3.3743x; 3.3743x over previous
//
#include <hip/hip_runtime.h>
#include <stdint.h>

// GraphPropLayer on MI355X — round 3: atomic-free CSR gather replaces k_edge.
//
// agg = segsum_t(relu fwd) + segsum_f(relu rev); gi folded through Gcat:
// gi = S @ Gcat.T + indeg*vf + outdeg*vr + b_ih, S[n] = [sum relu fwd | sum relu rev].
// Pipeline: prep -> CSR build (hist/scan/fill) -> K1 proj (T table, fp16) ->
//           k_gather (wave per node, reg accumulate) -> k_gru.

#define NN 50000
#define NE 512000

typedef unsigned short u16;
typedef unsigned int u32;

__device__ __forceinline__ float h2f(u16 u) {
  _Float16 h; __builtin_memcpy(&h, &u, 2); return (float)h;
}
__device__ __forceinline__ u16 f2h(float f) {
  _Float16 h = (_Float16)f; u16 u; __builtin_memcpy(&u, &h, 2); return u;
}

__device__ __forceinline__ void store8v(float* p, const float* v) {
  *(float4*)p       = make_float4(v[0], v[1], v[2], v[3]);
  *(float4*)(p + 4) = make_float4(v[4], v[5], v[6], v[7]);
}
__device__ __forceinline__ void store8v(u16* p, const float* v) {
  u16 t[8];
#pragma unroll
  for (int j = 0; j < 8; ++j) t[j] = f2h(v[j]);
  *(uint4*)p = *(const uint4*)t;
}
__device__ __forceinline__ float4 load4v(const float* p) { return *(const float4*)p; }
__device__ __forceinline__ float4 load4v(const u16* p) {
  ushort4 u = *(const ushort4*)p;
  return make_float4(h2f(u.x), h2f(u.y), h2f(u.z), h2f(u.w));
}
__device__ __forceinline__ void store4v(float* p, float4 v) { *(float4*)p = v; }
__device__ __forceinline__ void store4v(u16* p, float4 v) {
  u16 t[4] = {f2h(v.x), f2h(v.y), f2h(v.z), f2h(v.w)};
  *(ushort4*)p = *(const ushort4*)t;
}

// ---------------- prep kernels (tiny) ----------------

// Wcat[1024][128]; T col c semantics:
// [0,256): Wf1[:, 0:128] (+bf1) | [256,512): Wr1[:,128:256] | [512,768): Wf1[:,128:256]
// | [768,1024): Wr1[:,0:128] (+br1)
__global__ void k_wcat(const float* __restrict__ Wf1, const float* __restrict__ bf1,
                       const float* __restrict__ Wr1, const float* __restrict__ br1,
                       float* __restrict__ Wcat, float* __restrict__ biascat) {
  int c = blockIdx.x;
  int k = threadIdx.x;
  const float* src;
  if (c < 256)      src = Wf1 + (size_t)c * 256;
  else if (c < 512) src = Wr1 + (size_t)(c - 256) * 256 + 128;
  else if (c < 768) src = Wf1 + (size_t)(c - 512) * 256 + 128;
  else              src = Wr1 + (size_t)(c - 768) * 256;
  Wcat[(size_t)c * 128 + k] = src[k];
  if (k == 0) biascat[c] = (c < 256) ? bf1[c] : ((c >= 768) ? br1[c - 768] : 0.f);
}

// Gcat[384][512] = [W_ih@Wf2 | W_ih@Wr2]
__global__ void k_gcat(const float* __restrict__ W_ih, const float* __restrict__ Wf2,
                       const float* __restrict__ Wr2, float* __restrict__ Gcat) {
  int b = blockIdx.x;
  int c = b % 384, w = b / 384;
  const float* W2 = w ? Wr2 : Wf2;
  int k = threadIdx.x;
  float acc = 0.f;
  for (int o = 0; o < 256; ++o)
    acc = fmaf(W_ih[(size_t)c * 256 + o], W2[(size_t)o * 256 + k], acc);
  Gcat[(size_t)c * 512 + (size_t)w * 256 + k] = acc;
}

__global__ void k_vbias(const float* __restrict__ W_ih, const float* __restrict__ bf2,
                        const float* __restrict__ br2, float* __restrict__ vf,
                        float* __restrict__ vr) {
  int c = blockIdx.x * blockDim.x + threadIdx.x;
  if (c >= 384) return;
  float a = 0.f, b = 0.f;
  for (int o = 0; o < 256; ++o) {
    float w = W_ih[(size_t)c * 256 + o];
    a = fmaf(w, bf2[o], a);
    b = fmaf(w, br2[o], b);
  }
  vf[c] = a; vr[c] = b;
}

// ---------------- CSR build ----------------
// cnt[0:NN] = indeg (by to), cnt[NN:2NN] = outdeg (by from)
__global__ void k_hist(const int* __restrict__ from, const int* __restrict__ to,
                       int* __restrict__ cnt) {
  int e = blockIdx.x * 256 + threadIdx.x;
  if (e < NE) {
    atomicAdd(cnt + to[e], 1);
    atomicAdd(cnt + NN + from[e], 1);
  }
}

// exclusive scan of cnt[0:2NN] -> off[0:2NN] (+ sentinel off[2NN]); cur = copy
__global__ __launch_bounds__(1024) void k_scan(const int* __restrict__ cnt,
                                               int* __restrict__ off,
                                               int* __restrict__ cur) {
  __shared__ int part[1024];
  const int N = 2 * NN;
  const int CH = (N + 1023) / 1024;  // 98
  int tid = threadIdx.x;
  int s0 = tid * CH, s1 = min(s0 + CH, N);
  int sum = 0;
  for (int i = s0; i < s1; ++i) sum += cnt[i];
  part[tid] = sum;
  __syncthreads();
  for (int d = 1; d < 1024; d <<= 1) {
    int v = (tid >= d) ? part[tid - d] : 0;
    __syncthreads();
    part[tid] += v;
    __syncthreads();
  }
  int run = (tid > 0) ? part[tid - 1] : 0;
  for (int i = s0; i < s1; ++i) {
    off[i] = run; cur[i] = run;
    run += cnt[i];
  }
  if (tid == 1023) off[N] = run;  // == total (2*NE)
}

// in-list of node t stores from[e]; out-list of node f stores to[e]
__global__ void k_fill(const int* __restrict__ from, const int* __restrict__ to,
                       int* __restrict__ cur, int* __restrict__ nbr) {
  int e = blockIdx.x * 256 + threadIdx.x;
  if (e < NE) {
    int f = from[e], t = to[e];
    nbr[atomicAdd(cur + t, 1)] = f;
    nbr[atomicAdd(cur + NN + f, 1)] = t;
  }
}

// ---------------- K1: projection table T[n][1024] = ns[n] @ Wcat.T + biascat ----------------
__global__ __launch_bounds__(256) void k_proj(const float* __restrict__ ns,
                                              const float* __restrict__ Wcat,
                                              const float* __restrict__ biascat,
                                              u16* __restrict__ T) {
  __shared__ float As[16][64];
  __shared__ float Bs[16][132];
  const int m0 = blockIdx.x * 64;
  const int c0 = blockIdx.y * 128;
  const int tid = threadIdx.x;
  const int tm = tid >> 4, tn = tid & 15;
  const int ar = tid >> 2, aq = tid & 3;
  float acc[4][8];
#pragma unroll
  for (int i = 0; i < 4; ++i)
#pragma unroll
    for (int j = 0; j < 8; ++j) acc[i][j] = 0.f;

  for (int kt = 0; kt < 8; ++kt) {
    const int k0 = kt * 16;
    __syncthreads();
    {
      int row = m0 + ar;
      float4 v = make_float4(0.f, 0.f, 0.f, 0.f);
      if (row < NN) v = *(const float4*)(ns + (size_t)row * 128 + k0 + aq * 4);
      As[aq * 4 + 0][ar] = v.x; As[aq * 4 + 1][ar] = v.y;
      As[aq * 4 + 2][ar] = v.z; As[aq * 4 + 3][ar] = v.w;
    }
#pragma unroll
    for (int s = 0; s < 2; ++s) {
      int idx = tid + s * 256;
      int ci = idx >> 2, q = idx & 3;
      float4 v = *(const float4*)(Wcat + (size_t)(c0 + ci) * 128 + k0 + q * 4);
      Bs[q * 4 + 0][ci] = v.x; Bs[q * 4 + 1][ci] = v.y;
      Bs[q * 4 + 2][ci] = v.z; Bs[q * 4 + 3][ci] = v.w;
    }
    __syncthreads();
#pragma unroll
    for (int kk = 0; kk < 16; ++kk) {
      float4 a  = *(const float4*)&As[kk][tm * 4];
      float4 b0 = *(const float4*)&Bs[kk][tn * 8];
      float4 b1 = *(const float4*)&Bs[kk][tn * 8 + 4];
      float av[4] = {a.x, a.y, a.z, a.w};
      float bv[8] = {b0.x, b0.y, b0.z, b0.w, b1.x, b1.y, b1.z, b1.w};
#pragma unroll
      for (int i = 0; i < 4; ++i)
#pragma unroll
        for (int j = 0; j < 8; ++j) acc[i][j] = fmaf(av[i], bv[j], acc[i][j]);
    }
  }
  float bias[8];
#pragma unroll
  for (int j = 0; j < 8; ++j) bias[j] = biascat[c0 + tn * 8 + j];
#pragma unroll
  for (int i = 0; i < 4; ++i) {
    int row = m0 + tm * 4 + i;
    if (row < NN) {
      float v[8];
#pragma unroll
      for (int j = 0; j < 8; ++j) v[j] = acc[i][j] + bias[j];
      store8v(T + (size_t)row * 1024 + c0 + tn * 8, v);
    }
  }
}

// ---------------- K2': CSR gather, atomic-free ----------------
// Wave per node. dir 0 (fwd, in-edges): S[n][j] = sum relu(T[f][j] + T[n][512+j]).
// dir 1 (rev, out-edges): S[n][256+j] = sum relu(T[n][256+j] + T[t][768+j]).
template <typename ST>
__global__ __launch_bounds__(256) void k_gather(const u16* __restrict__ T,
                                                const int* __restrict__ nbr,
                                                const int* __restrict__ off,
                                                ST* __restrict__ S) {
  const int lane = threadIdx.x & 63;
  const int n = blockIdx.x * 4 + (threadIdx.x >> 6);
  if (n >= NN) return;
  const u16* Tn = T + (size_t)n * 1024;

  for (int dir = 0; dir < 2; ++dir) {
    const int invofs = dir ? 256 : 512;
    const int gofs = dir ? 768 : 0;
    float4 inv = load4v(Tn + invofs + lane * 4);
    const int s = off[dir * NN + n];
    const int e = off[dir * NN + n + 1];
    float4 a0 = make_float4(0.f, 0.f, 0.f, 0.f);
    float4 a1 = make_float4(0.f, 0.f, 0.f, 0.f);
    for (int i = s; i < e; i += 64) {
      int nb = (i + lane < e) ? nbr[i + lane] : 0;
      int cnt = min(64, e - i);
      int k = 0;
      for (; k + 1 < cnt; k += 2) {
        int f0 = __shfl(nb, k);
        int f1 = __shfl(nb, k + 1);
        float4 v0 = load4v(T + (size_t)f0 * 1024 + gofs + lane * 4);
        float4 v1 = load4v(T + (size_t)f1 * 1024 + gofs + lane * 4);
        a0.x += fmaxf(inv.x + v0.x, 0.f); a1.x += fmaxf(inv.x + v1.x, 0.f);
        a0.y += fmaxf(inv.y + v0.y, 0.f); a1.y += fmaxf(inv.y + v1.y, 0.f);
        a0.z += fmaxf(inv.z + v0.z, 0.f); a1.z += fmaxf(inv.z + v1.z, 0.f);
        a0.w += fmaxf(inv.w + v0.w, 0.f); a1.w += fmaxf(inv.w + v1.w, 0.f);
      }
      if (k < cnt) {
        int f0 = __shfl(nb, k);
        float4 v0 = load4v(T + (size_t)f0 * 1024 + gofs + lane * 4);
        a0.x += fmaxf(inv.x + v0.x, 0.f);
        a0.y += fmaxf(inv.y + v0.y, 0.f);
        a0.z += fmaxf(inv.z + v0.z, 0.f);
        a0.w += fmaxf(inv.w + v0.w, 0.f);
      }
    }
    a0.x += a1.x; a0.y += a1.y; a0.z += a1.z; a0.w += a1.w;
    store4v(S + (size_t)n * 512 + dir * 256 + lane * 4, a0);
  }
}

// ---------------- K3: fused GRU ----------------
template <typename ST>
__global__ __launch_bounds__(256) void k_gru(const ST* __restrict__ S,
                                             const float* __restrict__ ns,
                                             const float* __restrict__ Gcat,
                                             const float* __restrict__ W_hh,
                                             const float* __restrict__ b_ih,
                                             const float* __restrict__ b_hh,
                                             const float* __restrict__ vf,
                                             const float* __restrict__ vr,
                                             const int* __restrict__ off,
                                             float* __restrict__ out) {
  __shared__ float As[16][64];
  __shared__ float Bs[16][388];
  __shared__ u16 ghs[64][384];
  const int m0 = blockIdx.x * 64;
  const int tid = threadIdx.x;
  const int tm = tid >> 4, tn = tid & 15;
  const int ar = tid >> 2, aq = tid & 3;
  float acc[4][24];

  // ---- step A: gh = ns @ W_hh.T + b_hh -> fp16 LDS ----
#pragma unroll
  for (int i = 0; i < 4; ++i)
#pragma unroll
    for (int j = 0; j < 24; ++j) acc[i][j] = 0.f;

  for (int kt = 0; kt < 8; ++kt) {
    const int k0 = kt * 16;
    __syncthreads();
    {
      int row = m0 + ar;
      float4 v = make_float4(0.f, 0.f, 0.f, 0.f);
      if (row < NN) v = *(const float4*)(ns + (size_t)row * 128 + k0 + aq * 4);
      As[aq * 4 + 0][ar] = v.x; As[aq * 4 + 1][ar] = v.y;
      As[aq * 4 + 2][ar] = v.z; As[aq * 4 + 3][ar] = v.w;
    }
#pragma unroll
    for (int s = 0; s < 6; ++s) {
      int idx = tid + s * 256;
      int ci = idx >> 2, q = idx & 3;
      float4 v = *(const float4*)(W_hh + (size_t)ci * 128 + k0 + q * 4);
      Bs[q * 4 + 0][ci] = v.x; Bs[q * 4 + 1][ci] = v.y;
      Bs[q * 4 + 2][ci] = v.z; Bs[q * 4 + 3][ci] = v.w;
    }
    __syncthreads();
#pragma unroll
    for (int kk = 0; kk < 16; ++kk) {
      float4 a = *(const float4*)&As[kk][tm * 4];
      float av[4] = {a.x, a.y, a.z, a.w};
      float bv[24];
#pragma unroll
      for (int nt = 0; nt < 3; ++nt) {
        float4 b0 = *(const float4*)&Bs[kk][nt * 128 + tn * 8];
        float4 b1 = *(const float4*)&Bs[kk][nt * 128 + tn * 8 + 4];
        bv[nt * 8 + 0] = b0.x; bv[nt * 8 + 1] = b0.y; bv[nt * 8 + 2] = b0.z; bv[nt * 8 + 3] = b0.w;
        bv[nt * 8 + 4] = b1.x; bv[nt * 8 + 5] = b1.y; bv[nt * 8 + 6] = b1.z; bv[nt * 8 + 7] = b1.w;
      }
#pragma unroll
      for (int i = 0; i < 4; ++i)
#pragma unroll
        for (int j = 0; j < 24; ++j) acc[i][j] = fmaf(av[i], bv[j], acc[i][j]);
    }
  }
#pragma unroll
  for (int nt = 0; nt < 3; ++nt)
#pragma unroll
    for (int j = 0; j < 8; ++j) {
      int c = nt * 128 + tn * 8 + j;
      float bb = b_hh[c];
#pragma unroll
      for (int i = 0; i < 4; ++i) ghs[tm * 4 + i][c] = f2h(acc[i][nt * 8 + j] + bb);
    }

  // ---- step B: gi = S @ Gcat.T ----
#pragma unroll
  for (int i = 0; i < 4; ++i)
#pragma unroll
    for (int j = 0; j < 24; ++j) acc[i][j] = 0.f;

  for (int kt = 0; kt < 32; ++kt) {
    const int k0 = kt * 16;
    __syncthreads();
    {
      int row = m0 + ar;
      float4 v = make_float4(0.f, 0.f, 0.f, 0.f);
      if (row < NN) v = load4v(S + (size_t)row * 512 + k0 + aq * 4);
      As[aq * 4 + 0][ar] = v.x; As[aq * 4 + 1][ar] = v.y;
      As[aq * 4 + 2][ar] = v.z; As[aq * 4 + 3][ar] = v.w;
    }
#pragma unroll
    for (int s = 0; s < 6; ++s) {
      int idx = tid + s * 256;
      int ci = idx >> 2, q = idx & 3;
      float4 v = *(const float4*)(Gcat + (size_t)ci * 512 + k0 + q * 4);
      Bs[q * 4 + 0][ci] = v.x; Bs[q * 4 + 1][ci] = v.y;
      Bs[q * 4 + 2][ci] = v.z; Bs[q * 4 + 3][ci] = v.w;
    }
    __syncthreads();
#pragma unroll
    for (int kk = 0; kk < 16; ++kk) {
      float4 a = *(const float4*)&As[kk][tm * 4];
      float av[4] = {a.x, a.y, a.z, a.w};
      float bv[24];
#pragma unroll
      for (int nt = 0; nt < 3; ++nt) {
        float4 b0 = *(const float4*)&Bs[kk][nt * 128 + tn * 8];
        float4 b1 = *(const float4*)&Bs[kk][nt * 128 + tn * 8 + 4];
        bv[nt * 8 + 0] = b0.x; bv[nt * 8 + 1] = b0.y; bv[nt * 8 + 2] = b0.z; bv[nt * 8 + 3] = b0.w;
        bv[nt * 8 + 4] = b1.x; bv[nt * 8 + 5] = b1.y; bv[nt * 8 + 6] = b1.z; bv[nt * 8 + 7] = b1.w;
      }
#pragma unroll
      for (int i = 0; i < 4; ++i)
#pragma unroll
        for (int j = 0; j < 24; ++j) acc[i][j] = fmaf(av[i], bv[j], acc[i][j]);
    }
  }

  // ---- epilogue: gates ----
#pragma unroll
  for (int i = 0; i < 4; ++i) {
    int row = m0 + tm * 4 + i;
    if (row >= NN) continue;
    float idg = (float)(off[row + 1] - off[row]);
    float odg = (float)(off[NN + row + 1] - off[NN + row]);
    float ov[8];
#pragma unroll
    for (int j = 0; j < 8; ++j) {
      int d = tn * 8 + j;
      float gi0 = acc[i][j]      + idg * vf[d]       + odg * vr[d]       + b_ih[d];
      float gi1 = acc[i][8 + j]  + idg * vf[128 + d] + odg * vr[128 + d] + b_ih[128 + d];
      float gi2 = acc[i][16 + j] + idg * vf[256 + d] + odg * vr[256 + d] + b_ih[256 + d];
      int r = tm * 4 + i;
      float hr = h2f(ghs[r][d]);
      float hz = h2f(ghs[r][128 + d]);
      float hn = h2f(ghs[r][256 + d]);
      float rg = 1.f / (1.f + __expf(-(gi0 + hr)));
      float zg = 1.f / (1.f + __expf(-(gi1 + hz)));
      float ng = tanhf(gi2 + rg * hn);
      float h = ns[(size_t)row * 128 + d];
      ov[j] = (1.f - zg) * ng + zg * h;
    }
    store8v(out + (size_t)row * 128 + tn * 8, ov);
  }
}

// ---------------- launch ----------------
extern "C" void kernel_launch(void* const* d_in, const int* in_sizes, int n_in,
                              void* d_out, int out_size, void* d_ws, size_t ws_size,
                              hipStream_t stream) {
  const float* ns   = (const float*)d_in[0];
  const int* from   = (const int*)d_in[1];
  const int* to     = (const int*)d_in[2];
  const float* Wf1  = (const float*)d_in[3];
  const float* bf1  = (const float*)d_in[4];
  const float* Wf2  = (const float*)d_in[5];
  const float* bf2  = (const float*)d_in[6];
  const float* Wr1  = (const float*)d_in[7];
  const float* br1  = (const float*)d_in[8];
  const float* Wr2  = (const float*)d_in[9];
  const float* br2  = (const float*)d_in[10];
  const float* W_ih = (const float*)d_in[11];
  const float* W_hh = (const float*)d_in[12];
  const float* b_ih = (const float*)d_in[13];
  const float* b_hh = (const float*)d_in[14];
  float* out = (float*)d_out;

  // workspace layout
  char* w = (char*)d_ws;
  float* Wcat    = (float*)(w + 0);          // 524288
  float* biascat = (float*)(w + 524288);     // 4096
  float* Gcat    = (float*)(w + 528384);     // 786432
  float* vf      = (float*)(w + 1314816);    // 1536
  float* vr      = (float*)(w + 1316352);    // 1536
  int*   cnt     = (int*)(w + 1317888);      // 100000 ints -> 400128
  int*   off     = (int*)(w + 1718016);      // 100001 ints -> 400128
  int*   cur     = (int*)(w + 2118144);      // 100000 ints -> 400128
  int*   nbr     = (int*)(w + 2518272);      // 1024000 ints = 4096000
  u16*   T       = (u16*)(w + 6614272);      // 50000*1024*2 = 102400000
  void*  Sp      = (void*)(w + 109014272);   // S: fp32 102400000 or fp16 51200000

  const unsigned long long NEED_SF32 = 211414272ull;
  bool s32 = (ws_size >= NEED_SF32);

  hipMemsetAsync(cnt, 0, 400000, stream);

  k_wcat<<<1024, 128, 0, stream>>>(Wf1, bf1, Wr1, br1, Wcat, biascat);
  k_gcat<<<768, 256, 0, stream>>>(W_ih, Wf2, Wr2, Gcat);
  k_vbias<<<3, 128, 0, stream>>>(W_ih, bf2, br2, vf, vr);

  k_hist<<<(NE + 255) / 256, 256, 0, stream>>>(from, to, cnt);
  k_scan<<<1, 1024, 0, stream>>>(cnt, off, cur);
  k_fill<<<(NE + 255) / 256, 256, 0, stream>>>(from, to, cur, nbr);

  k_proj<<<dim3(782, 8), 256, 0, stream>>>(ns, Wcat, biascat, T);

  if (s32) {
    k_gather<float><<<12500, 256, 0, stream>>>(T, nbr, off, (float*)Sp);
    k_gru<float><<<782, 256, 0, stream>>>((const float*)Sp, ns, Gcat, W_hh, b_ih, b_hh,
                                          vf, vr, off, out);
  } else {
    k_gather<u16><<<12500, 256, 0, stream>>>(T, nbr, off, (u16*)Sp);
    k_gru<u16><<<782, 256, 0, stream>>>((const u16*)Sp, ns, Gcat, W_hh, b_ih, b_hh,
                                        vf, vr, off, out);
  }
}

// Round 4
// 634.256 us; speedup vs baseline: 6.9730x; 2.0665x over previous
//
#include <hip/hip_runtime.h>
#include <stdint.h>

// GraphPropLayer on MI355X — round 4: MFMA (f16 in, f32 acc) for k_proj & k_gru,
// all operands pre-swizzled into MFMA fragment layout; LDS-free GEMM kernels.
//
// Fragment layout (v_mfma_f32_16x16x32_f16):
//   A (16m x 32k): lane = row + 16*((k%32)/8), elem j = k%8
//   B (32k x 16n): lane = col + 16*((k%32)/8), elem j = k%8
//   C/D: col = lane&15, row = (lane>>4)*4 + reg
// Tile = 512 halfs (1 KB); buffers indexed [(mt_or_nt * KT + kt)*512 + lane*8 + j].

#define NN 50000
#define NE 512000

typedef unsigned short u16;
typedef unsigned int u32;
using h8  = __attribute__((ext_vector_type(8))) _Float16;
using f4v = __attribute__((ext_vector_type(4))) float;

__device__ __forceinline__ float h2f(u16 u) {
  _Float16 h; __builtin_memcpy(&h, &u, 2); return (float)h;
}
__device__ __forceinline__ u16 f2h(float f) {
  _Float16 h = (_Float16)f; u16 u; __builtin_memcpy(&u, &h, 2); return u;
}
__device__ __forceinline__ float4 load4h(const u16* p) {
  ushort4 u = *(const ushort4*)p;
  return make_float4(h2f(u.x), h2f(u.y), h2f(u.z), h2f(u.w));
}

// ---------------- prep kernels (tiny) ----------------

// Wcat fragment (64 nt x 4 kt). T col c semantics (unchanged):
// [0,256): Wf1[:,0:128](+bf1) | [256,512): Wr1[:,128:256] | [512,768): Wf1[:,128:256]
// | [768,1024): Wr1[:,0:128](+br1)
__global__ void k_wcat(const float* __restrict__ Wf1, const float* __restrict__ bf1,
                       const float* __restrict__ Wr1, const float* __restrict__ br1,
                       u16* __restrict__ Wc16, float* __restrict__ biascat) {
  int c = blockIdx.x;
  int k = threadIdx.x;
  const float* src;
  if (c < 256)      src = Wf1 + (size_t)c * 256;
  else if (c < 512) src = Wr1 + (size_t)(c - 256) * 256 + 128;
  else if (c < 768) src = Wf1 + (size_t)(c - 512) * 256 + 128;
  else              src = Wr1 + (size_t)(c - 768) * 256;
  float v = src[k];
  int nt = c >> 4, kt = k >> 5, g = (k & 31) >> 3, j = k & 7;
  int lane = (c & 15) + g * 16;
  Wc16[((size_t)nt * 4 + kt) * 512 + lane * 8 + j] = f2h(v);
  if (k == 0) biascat[c] = (c < 256) ? bf1[c] : ((c >= 768) ? br1[c - 768] : 0.f);
}

// Gcat fragment (24 nt x 16 kt): Gcat[c][k] = sum_o W_ih[c][o] * W2[o][k']
__global__ void k_gcat(const float* __restrict__ W_ih, const float* __restrict__ Wf2,
                       const float* __restrict__ Wr2, u16* __restrict__ G16) {
  int b = blockIdx.x;
  int c = b % 384, w = b / 384;
  const float* W2 = w ? Wr2 : Wf2;
  int k = threadIdx.x;  // 0..255 within W2
  float acc = 0.f;
  for (int o = 0; o < 256; ++o)
    acc = fmaf(W_ih[(size_t)c * 256 + o], W2[(size_t)o * 256 + k], acc);
  int kg = w * 256 + k;  // 0..511
  int nt = c >> 4, kt = kg >> 5, g = (kg & 31) >> 3, j = kg & 7;
  int lane = (c & 15) + g * 16;
  G16[((size_t)nt * 16 + kt) * 512 + lane * 8 + j] = f2h(acc);
}

// W_hh fragment (24 nt x 4 kt)
__global__ void k_whh(const float* __restrict__ W_hh, u16* __restrict__ Wh16) {
  int c = blockIdx.x, k = threadIdx.x;
  float v = W_hh[(size_t)c * 128 + k];
  int nt = c >> 4, kt = k >> 5, g = (k & 31) >> 3, j = k & 7;
  int lane = (c & 15) + g * 16;
  Wh16[((size_t)nt * 4 + kt) * 512 + lane * 8 + j] = f2h(v);
}

__global__ void k_vbias(const float* __restrict__ W_ih, const float* __restrict__ bf2,
                        const float* __restrict__ br2, float* __restrict__ vf,
                        float* __restrict__ vr) {
  int c = blockIdx.x * blockDim.x + threadIdx.x;
  if (c >= 384) return;
  float a = 0.f, b = 0.f;
  for (int o = 0; o < 256; ++o) {
    float w = W_ih[(size_t)c * 256 + o];
    a = fmaf(w, bf2[o], a);
    b = fmaf(w, br2[o], b);
  }
  vf[c] = a; vr[c] = b;
}

// ns -> fp16 A-fragment (3125 mt x 4 kt)
__global__ void k_nsh(const float* __restrict__ ns, u16* __restrict__ nsf) {
  int t = blockIdx.x * 256 + threadIdx.x;
  int n = t >> 4, kk8 = t & 15;
  float4 v0 = *(const float4*)(ns + (size_t)n * 128 + kk8 * 8);
  float4 v1 = *(const float4*)(ns + (size_t)n * 128 + kk8 * 8 + 4);
  u16 hv[8] = {f2h(v0.x), f2h(v0.y), f2h(v0.z), f2h(v0.w),
               f2h(v1.x), f2h(v1.y), f2h(v1.z), f2h(v1.w)};
  int mt = n >> 4, r = n & 15, kt = kk8 >> 2, g = kk8 & 3;
  int lane = r + g * 16;
  *(uint4*)(nsf + ((size_t)mt * 4 + kt) * 512 + lane * 8) = *(const uint4*)hv;
}

// ---------------- CSR build ----------------
__global__ void k_hist(const int* __restrict__ from, const int* __restrict__ to,
                       int* __restrict__ cnt) {
  int e = blockIdx.x * 256 + threadIdx.x;
  if (e < NE) {
    atomicAdd(cnt + to[e], 1);
    atomicAdd(cnt + NN + from[e], 1);
  }
}

__global__ __launch_bounds__(1024) void k_scan(const int* __restrict__ cnt,
                                               int* __restrict__ off,
                                               int* __restrict__ cur) {
  __shared__ int part[1024];
  const int N = 2 * NN;
  const int CH = (N + 1023) / 1024;
  int tid = threadIdx.x;
  int s0 = tid * CH, s1 = min(s0 + CH, N);
  int sum = 0;
  for (int i = s0; i < s1; ++i) sum += cnt[i];
  part[tid] = sum;
  __syncthreads();
  for (int d = 1; d < 1024; d <<= 1) {
    int v = (tid >= d) ? part[tid - d] : 0;
    __syncthreads();
    part[tid] += v;
    __syncthreads();
  }
  int run = (tid > 0) ? part[tid - 1] : 0;
  for (int i = s0; i < s1; ++i) {
    off[i] = run; cur[i] = run;
    run += cnt[i];
  }
  if (tid == 1023) off[N] = run;
}

__global__ void k_fill(const int* __restrict__ from, const int* __restrict__ to,
                       int* __restrict__ cur, int* __restrict__ nbr) {
  int e = blockIdx.x * 256 + threadIdx.x;
  if (e < NE) {
    int f = from[e], t = to[e];
    nbr[atomicAdd(cur + t, 1)] = f;
    nbr[atomicAdd(cur + NN + f, 1)] = t;
  }
}

// ---------------- K1: MFMA projection, T[n][1024] row-major fp16 ----------------
// grid 3125 (16 rows each), 4 waves; wave w covers n-tiles w*16..w*16+15.
__global__ __launch_bounds__(256) void k_proj(const u16* __restrict__ nsf,
                                              const u16* __restrict__ Wc16,
                                              const float* __restrict__ biascat,
                                              u16* __restrict__ T) {
  const int w = threadIdx.x >> 6, lane = threadIdx.x & 63;
  const int mt = blockIdx.x;
  f4v acc[16];
#pragma unroll
  for (int t = 0; t < 16; ++t) acc[t] = (f4v){0.f, 0.f, 0.f, 0.f};

#pragma unroll
  for (int kt = 0; kt < 4; ++kt) {
    h8 a = *(const h8*)(nsf + ((size_t)mt * 4 + kt) * 512 + lane * 8);
#pragma unroll
    for (int t = 0; t < 16; ++t) {
      int nt = w * 16 + t;
      h8 b = *(const h8*)(Wc16 + ((size_t)nt * 4 + kt) * 512 + lane * 8);
      acc[t] = __builtin_amdgcn_mfma_f32_16x16x32_f16(a, b, acc[t], 0, 0, 0);
    }
  }
  const int c0 = lane & 15, rB = (lane >> 4) * 4;
#pragma unroll
  for (int t = 0; t < 16; ++t) {
    int col = (w * 16 + t) * 16 + c0;
    float bias = biascat[col];
#pragma unroll
    for (int reg = 0; reg < 4; ++reg) {
      int row = mt * 16 + rB + reg;
      T[(size_t)row * 1024 + col] = f2h(acc[t][reg] + bias);
    }
  }
}

// ---------------- K2: CSR gather -> S in A-fragment layout (fp16) ----------------
// Wave per node. dir 0 (in-edges): cols 0..255 = sum relu(T[f][c] + T[n][512+c]).
// dir 1 (out-edges): cols 256..511 = sum relu(T[n][256+c'] + T[t][768+c']).
__global__ __launch_bounds__(256) void k_gather(const u16* __restrict__ T,
                                                const int* __restrict__ nbr,
                                                const int* __restrict__ off,
                                                u16* __restrict__ Sf) {
  const int lane = threadIdx.x & 63;
  const int n = blockIdx.x * 4 + (threadIdx.x >> 6);
  if (n >= NN) return;
  const u16* Tn = T + (size_t)n * 1024;
  const int mt = n >> 4, r = n & 15;
  const int g = (lane & 7) >> 1, j0 = (lane & 1) * 4;
  const int laneF = r + g * 16;

  for (int dir = 0; dir < 2; ++dir) {
    const int invofs = dir ? 256 : 512;
    const int gofs = dir ? 768 : 0;
    float4 inv = load4h(Tn + invofs + lane * 4);
    const int s = off[dir * NN + n];
    const int e = off[dir * NN + n + 1];
    float4 a0 = make_float4(0.f, 0.f, 0.f, 0.f);
    float4 a1 = make_float4(0.f, 0.f, 0.f, 0.f);
    for (int i = s; i < e; i += 64) {
      int nb = (i + lane < e) ? nbr[i + lane] : 0;
      int cnt = min(64, e - i);
      int k = 0;
      for (; k + 1 < cnt; k += 2) {
        int f0 = __shfl(nb, k);
        int f1 = __shfl(nb, k + 1);
        float4 v0 = load4h(T + (size_t)f0 * 1024 + gofs + lane * 4);
        float4 v1 = load4h(T + (size_t)f1 * 1024 + gofs + lane * 4);
        a0.x += fmaxf(inv.x + v0.x, 0.f); a1.x += fmaxf(inv.x + v1.x, 0.f);
        a0.y += fmaxf(inv.y + v0.y, 0.f); a1.y += fmaxf(inv.y + v1.y, 0.f);
        a0.z += fmaxf(inv.z + v0.z, 0.f); a1.z += fmaxf(inv.z + v1.z, 0.f);
        a0.w += fmaxf(inv.w + v0.w, 0.f); a1.w += fmaxf(inv.w + v1.w, 0.f);
      }
      if (k < cnt) {
        int f0 = __shfl(nb, k);
        float4 v0 = load4h(T + (size_t)f0 * 1024 + gofs + lane * 4);
        a0.x += fmaxf(inv.x + v0.x, 0.f);
        a0.y += fmaxf(inv.y + v0.y, 0.f);
        a0.z += fmaxf(inv.z + v0.z, 0.f);
        a0.w += fmaxf(inv.w + v0.w, 0.f);
      }
    }
    a0.x += a1.x; a0.y += a1.y; a0.z += a1.z; a0.w += a1.w;
    // store to A-fragment layout: c_global = dir*256 + lane*4 + q
    int kt = dir * 8 + (lane >> 3);
    u16 hv[4] = {f2h(a0.x), f2h(a0.y), f2h(a0.z), f2h(a0.w)};
    *(ushort4*)(Sf + ((size_t)mt * 16 + kt) * 512 + laneF * 8 + j0) = *(const ushort4*)hv;
  }
}

// ---------------- K3: MFMA GRU, LDS-free ----------------
// grid 1563 (32 rows), 4 waves; wave w owns n-tiles {2w+p+8g}, so gate triplets
// (d, 128+d, 256+d) are lane-local. Epilogue entirely in registers.
__global__ __launch_bounds__(256) void k_gru(const u16* __restrict__ Sf,
                                             const u16* __restrict__ nsf,
                                             const u16* __restrict__ G16,
                                             const u16* __restrict__ Wh16,
                                             const float* __restrict__ ns,
                                             const float* __restrict__ b_ih,
                                             const float* __restrict__ b_hh,
                                             const float* __restrict__ vf,
                                             const float* __restrict__ vr,
                                             const int* __restrict__ off,
                                             float* __restrict__ out) {
  const int w = threadIdx.x >> 6, lane = threadIdx.x & 63;
  const int mt0 = blockIdx.x * 2;
  const bool v0 = (mt0 * 16) < NN;
  const bool v1 = ((mt0 + 1) * 16) < NN;
  const h8 hz = {(_Float16)0.f, (_Float16)0.f, (_Float16)0.f, (_Float16)0.f,
                 (_Float16)0.f, (_Float16)0.f, (_Float16)0.f, (_Float16)0.f};

  f4v gh[2][2][3], gi[2][2][3];
#pragma unroll
  for (int a = 0; a < 2; ++a)
#pragma unroll
    for (int p = 0; p < 2; ++p)
#pragma unroll
      for (int g = 0; g < 3; ++g) {
        gh[a][p][g] = (f4v){0.f, 0.f, 0.f, 0.f};
        gi[a][p][g] = (f4v){0.f, 0.f, 0.f, 0.f};
      }

  // step A: gh = ns @ W_hh.T (K=128)
#pragma unroll
  for (int kt = 0; kt < 4; ++kt) {
    h8 a0 = v0 ? *(const h8*)(nsf + ((size_t)mt0 * 4 + kt) * 512 + lane * 8) : hz;
    h8 a1 = v1 ? *(const h8*)(nsf + ((size_t)(mt0 + 1) * 4 + kt) * 512 + lane * 8) : hz;
#pragma unroll
    for (int g = 0; g < 3; ++g)
#pragma unroll
      for (int p = 0; p < 2; ++p) {
        int nt = 2 * w + p + 8 * g;
        h8 b = *(const h8*)(Wh16 + ((size_t)nt * 4 + kt) * 512 + lane * 8);
        gh[0][p][g] = __builtin_amdgcn_mfma_f32_16x16x32_f16(a0, b, gh[0][p][g], 0, 0, 0);
        gh[1][p][g] = __builtin_amdgcn_mfma_f32_16x16x32_f16(a1, b, gh[1][p][g], 0, 0, 0);
      }
  }

  // step B: gi = S @ Gcat.T (K=512)
#pragma unroll
  for (int kt = 0; kt < 16; ++kt) {
    h8 a0 = v0 ? *(const h8*)(Sf + ((size_t)mt0 * 16 + kt) * 512 + lane * 8) : hz;
    h8 a1 = v1 ? *(const h8*)(Sf + ((size_t)(mt0 + 1) * 16 + kt) * 512 + lane * 8) : hz;
#pragma unroll
    for (int g = 0; g < 3; ++g)
#pragma unroll
      for (int p = 0; p < 2; ++p) {
        int nt = 2 * w + p + 8 * g;
        h8 b = *(const h8*)(G16 + ((size_t)nt * 16 + kt) * 512 + lane * 8);
        gi[0][p][g] = __builtin_amdgcn_mfma_f32_16x16x32_f16(a0, b, gi[0][p][g], 0, 0, 0);
        gi[1][p][g] = __builtin_amdgcn_mfma_f32_16x16x32_f16(a1, b, gi[1][p][g], 0, 0, 0);
      }
  }

  // epilogue
  const int c0 = lane & 15, rB = (lane >> 4) * 4;
#pragma unroll
  for (int a = 0; a < 2; ++a) {
    if (!(a ? v1 : v0)) continue;
    const int mt = mt0 + a;
    float idg[4], odg[4];
#pragma unroll
    for (int reg = 0; reg < 4; ++reg) {
      int row = mt * 16 + rB + reg;
      idg[reg] = (float)(off[row + 1] - off[row]);
      odg[reg] = (float)(off[NN + row + 1] - off[NN + row]);
    }
#pragma unroll
    for (int p = 0; p < 2; ++p) {
      int d = (2 * w + p) * 16 + c0;
      float vf0 = vf[d], vf1 = vf[128 + d], vf2 = vf[256 + d];
      float vr0 = vr[d], vr1 = vr[128 + d], vr2 = vr[256 + d];
      float bi0 = b_ih[d], bi1 = b_ih[128 + d], bi2 = b_ih[256 + d];
      float bh0 = b_hh[d], bh1 = b_hh[128 + d], bh2 = b_hh[256 + d];
#pragma unroll
      for (int reg = 0; reg < 4; ++reg) {
        int row = mt * 16 + rB + reg;
        float gr = gi[a][p][0][reg] + idg[reg] * vf0 + odg[reg] * vr0 + bi0;
        float gz = gi[a][p][1][reg] + idg[reg] * vf1 + odg[reg] * vr1 + bi1;
        float gn = gi[a][p][2][reg] + idg[reg] * vf2 + odg[reg] * vr2 + bi2;
        float hr = gh[a][p][0][reg] + bh0;
        float hzv = gh[a][p][1][reg] + bh1;
        float hn = gh[a][p][2][reg] + bh2;
        float rg = 1.f / (1.f + __expf(-(gr + hr)));
        float zg = 1.f / (1.f + __expf(-(gz + hzv)));
        float ng = tanhf(gn + rg * hn);
        float h = ns[(size_t)row * 128 + d];
        out[(size_t)row * 128 + d] = (1.f - zg) * ng + zg * h;
      }
    }
  }
}

// ---------------- launch ----------------
extern "C" void kernel_launch(void* const* d_in, const int* in_sizes, int n_in,
                              void* d_out, int out_size, void* d_ws, size_t ws_size,
                              hipStream_t stream) {
  const float* ns   = (const float*)d_in[0];
  const int* from   = (const int*)d_in[1];
  const int* to     = (const int*)d_in[2];
  const float* Wf1  = (const float*)d_in[3];
  const float* bf1  = (const float*)d_in[4];
  const float* Wf2  = (const float*)d_in[5];
  const float* bf2  = (const float*)d_in[6];
  const float* Wr1  = (const float*)d_in[7];
  const float* br1  = (const float*)d_in[8];
  const float* Wr2  = (const float*)d_in[9];
  const float* br2  = (const float*)d_in[10];
  const float* W_ih = (const float*)d_in[11];
  const float* W_hh = (const float*)d_in[12];
  const float* b_ih = (const float*)d_in[13];
  const float* b_hh = (const float*)d_in[14];
  float* out = (float*)d_out;

  // workspace layout (all 256B aligned)
  char* w = (char*)d_ws;
  u16*   Wc16    = (u16*)(w + 0);            // 1024*128*2 = 262144
  float* biascat = (float*)(w + 262144);     // 4096
  u16*   G16     = (u16*)(w + 266240);       // 384*512*2 = 393216
  u16*   Wh16    = (u16*)(w + 659456);       // 384*128*2 = 98304
  float* vf      = (float*)(w + 757760);     // 1536
  float* vr      = (float*)(w + 759296);     // 1536
  int*   cnt     = (int*)(w + 760832);       // 400128
  int*   off     = (int*)(w + 1160960);      // 400128
  int*   cur     = (int*)(w + 1561088);      // 400128
  int*   nbr     = (int*)(w + 1961216);      // 4096000
  u16*   nsf     = (u16*)(w + 6057216);      // 3125*4*512*2 = 12800000
  u16*   T       = (u16*)(w + 18857216);     // 50000*1024*2 = 102400000
  u16*   Sf      = (u16*)(w + 121257216);    // 3125*16*512*2 = 51200000
  // total 172457216 bytes (< 211MB proven available in round 3)

  hipMemsetAsync(cnt, 0, 400000, stream);

  k_wcat<<<1024, 128, 0, stream>>>(Wf1, bf1, Wr1, br1, Wc16, biascat);
  k_gcat<<<768, 256, 0, stream>>>(W_ih, Wf2, Wr2, G16);
  k_whh<<<384, 128, 0, stream>>>(W_hh, Wh16);
  k_vbias<<<3, 128, 0, stream>>>(W_ih, bf2, br2, vf, vr);
  k_nsh<<<3125, 256, 0, stream>>>(ns, nsf);

  k_hist<<<(NE + 255) / 256, 256, 0, stream>>>(from, to, cnt);
  k_scan<<<1, 1024, 0, stream>>>(cnt, off, cur);
  k_fill<<<(NE + 255) / 256, 256, 0, stream>>>(from, to, cur, nbr);

  k_proj<<<3125, 256, 0, stream>>>(nsf, Wc16, biascat, T);
  k_gather<<<12500, 256, 0, stream>>>(T, nbr, off, Sf);
  k_gru<<<1563, 256, 0, stream>>>(Sf, nsf, G16, Wh16, ns, b_ih, b_hh, vf, vr, off, out);
}

// Round 5
// 416.285 us; speedup vs baseline: 10.6242x; 1.5236x over previous
//
#include <hip/hip_runtime.h>
#include <stdint.h>

// GraphPropLayer on MI355X — round 5: multi-block CSR scan (was 228µs single-block),
// 4-deep unrolled gather. MFMA GEMMs unchanged from round 4.
//
// Fragment layout (v_mfma_f32_16x16x32_f16):
//   A (16m x 32k): lane = row + 16*((k%32)/8), elem j = k%8
//   B (32k x 16n): lane = col + 16*((k%32)/8), elem j = k%8
//   C/D: col = lane&15, row = (lane>>4)*4 + reg
// Tile = 512 halfs (1 KB); buffers indexed [(mt_or_nt * KT + kt)*512 + lane*8 + j].

#define NN 50000
#define NE 512000
#define SCAN_N (2 * NN)
#define SCAN_BLOCKS ((SCAN_N + 1023) / 1024)  // 98

typedef unsigned short u16;
typedef unsigned int u32;
using h8  = __attribute__((ext_vector_type(8))) _Float16;
using f4v = __attribute__((ext_vector_type(4))) float;

__device__ __forceinline__ float h2f(u16 u) {
  _Float16 h; __builtin_memcpy(&h, &u, 2); return (float)h;
}
__device__ __forceinline__ u16 f2h(float f) {
  _Float16 h = (_Float16)f; u16 u; __builtin_memcpy(&u, &h, 2); return u;
}
__device__ __forceinline__ float4 load4h(const u16* p) {
  ushort4 u = *(const ushort4*)p;
  return make_float4(h2f(u.x), h2f(u.y), h2f(u.z), h2f(u.w));
}

// ---------------- prep kernels (tiny) ----------------

// Wcat fragment (64 nt x 4 kt). T col c semantics:
// [0,256): Wf1[:,0:128](+bf1) | [256,512): Wr1[:,128:256] | [512,768): Wf1[:,128:256]
// | [768,1024): Wr1[:,0:128](+br1)
__global__ void k_wcat(const float* __restrict__ Wf1, const float* __restrict__ bf1,
                       const float* __restrict__ Wr1, const float* __restrict__ br1,
                       u16* __restrict__ Wc16, float* __restrict__ biascat) {
  int c = blockIdx.x;
  int k = threadIdx.x;
  const float* src;
  if (c < 256)      src = Wf1 + (size_t)c * 256;
  else if (c < 512) src = Wr1 + (size_t)(c - 256) * 256 + 128;
  else if (c < 768) src = Wf1 + (size_t)(c - 512) * 256 + 128;
  else              src = Wr1 + (size_t)(c - 768) * 256;
  float v = src[k];
  int nt = c >> 4, kt = k >> 5, g = (k & 31) >> 3, j = k & 7;
  int lane = (c & 15) + g * 16;
  Wc16[((size_t)nt * 4 + kt) * 512 + lane * 8 + j] = f2h(v);
  if (k == 0) biascat[c] = (c < 256) ? bf1[c] : ((c >= 768) ? br1[c - 768] : 0.f);
}

// Gcat fragment (24 nt x 16 kt)
__global__ void k_gcat(const float* __restrict__ W_ih, const float* __restrict__ Wf2,
                       const float* __restrict__ Wr2, u16* __restrict__ G16) {
  int b = blockIdx.x;
  int c = b % 384, w = b / 384;
  const float* W2 = w ? Wr2 : Wf2;
  int k = threadIdx.x;
  float acc = 0.f;
  for (int o = 0; o < 256; ++o)
    acc = fmaf(W_ih[(size_t)c * 256 + o], W2[(size_t)o * 256 + k], acc);
  int kg = w * 256 + k;
  int nt = c >> 4, kt = kg >> 5, g = (kg & 31) >> 3, j = kg & 7;
  int lane = (c & 15) + g * 16;
  G16[((size_t)nt * 16 + kt) * 512 + lane * 8 + j] = f2h(acc);
}

// W_hh fragment (24 nt x 4 kt)
__global__ void k_whh(const float* __restrict__ W_hh, u16* __restrict__ Wh16) {
  int c = blockIdx.x, k = threadIdx.x;
  float v = W_hh[(size_t)c * 128 + k];
  int nt = c >> 4, kt = k >> 5, g = (k & 31) >> 3, j = k & 7;
  int lane = (c & 15) + g * 16;
  Wh16[((size_t)nt * 4 + kt) * 512 + lane * 8 + j] = f2h(v);
}

__global__ void k_vbias(const float* __restrict__ W_ih, const float* __restrict__ bf2,
                        const float* __restrict__ br2, float* __restrict__ vf,
                        float* __restrict__ vr) {
  int c = blockIdx.x * blockDim.x + threadIdx.x;
  if (c >= 384) return;
  float a = 0.f, b = 0.f;
  for (int o = 0; o < 256; ++o) {
    float w = W_ih[(size_t)c * 256 + o];
    a = fmaf(w, bf2[o], a);
    b = fmaf(w, br2[o], b);
  }
  vf[c] = a; vr[c] = b;
}

// ns -> fp16 A-fragment (3125 mt x 4 kt)
__global__ void k_nsh(const float* __restrict__ ns, u16* __restrict__ nsf) {
  int t = blockIdx.x * 256 + threadIdx.x;
  int n = t >> 4, kk8 = t & 15;
  float4 v0 = *(const float4*)(ns + (size_t)n * 128 + kk8 * 8);
  float4 v1 = *(const float4*)(ns + (size_t)n * 128 + kk8 * 8 + 4);
  u16 hv[8] = {f2h(v0.x), f2h(v0.y), f2h(v0.z), f2h(v0.w),
               f2h(v1.x), f2h(v1.y), f2h(v1.z), f2h(v1.w)};
  int mt = n >> 4, r = n & 15, kt = kk8 >> 2, g = kk8 & 3;
  int lane = r + g * 16;
  *(uint4*)(nsf + ((size_t)mt * 4 + kt) * 512 + lane * 8) = *(const uint4*)hv;
}

// ---------------- CSR build ----------------
__global__ void k_hist(const int* __restrict__ from, const int* __restrict__ to,
                       int* __restrict__ cnt) {
  int e = blockIdx.x * 256 + threadIdx.x;
  if (e < NE) {
    atomicAdd(cnt + to[e], 1);
    atomicAdd(cnt + NN + from[e], 1);
  }
}

// scan phase A: per-block (1024 elems) sums, coalesced int4
__global__ __launch_bounds__(256) void k_scanA(const int* __restrict__ cnt,
                                               int* __restrict__ bsum) {
  __shared__ int part[256];
  int b = blockIdx.x, tid = threadIdx.x;
  int idx = b * 1024 + tid * 4;
  int s = 0;
  if (idx + 3 < SCAN_N) {
    int4 v = *(const int4*)(cnt + idx);
    s = v.x + v.y + v.z + v.w;
  } else {
    for (int q = 0; q < 4; ++q)
      if (idx + q < SCAN_N) s += cnt[idx + q];
  }
  part[tid] = s;
  __syncthreads();
  for (int d = 128; d > 0; d >>= 1) {
    if (tid < d) part[tid] += part[tid + d];
    __syncthreads();
  }
  if (tid == 0) bsum[b] = part[0];
}

// scan phase B: exclusive scan of the 98 block sums (single tiny block)
__global__ __launch_bounds__(128) void k_scanB(int* __restrict__ bsum) {
  __shared__ int part[128];
  int tid = threadIdx.x;
  int v = (tid < SCAN_BLOCKS) ? bsum[tid] : 0;
  part[tid] = v;
  __syncthreads();
  for (int d = 1; d < 128; d <<= 1) {
    int x = (tid >= d) ? part[tid - d] : 0;
    __syncthreads();
    part[tid] += x;
    __syncthreads();
  }
  if (tid < SCAN_BLOCKS) bsum[tid] = (tid > 0) ? part[tid - 1] : 0;
}

// scan phase C: per-block local scan + block offset -> off, cur
__global__ __launch_bounds__(256) void k_scanC(const int* __restrict__ cnt,
                                               const int* __restrict__ bsum,
                                               int* __restrict__ off,
                                               int* __restrict__ cur) {
  __shared__ int part[256];
  int b = blockIdx.x, tid = threadIdx.x;
  int idx = b * 1024 + tid * 4;
  int c[4] = {0, 0, 0, 0};
  if (idx + 3 < SCAN_N) {
    int4 v = *(const int4*)(cnt + idx);
    c[0] = v.x; c[1] = v.y; c[2] = v.z; c[3] = v.w;
  } else {
    for (int q = 0; q < 4; ++q)
      if (idx + q < SCAN_N) c[q] = cnt[idx + q];
  }
  int s = c[0] + c[1] + c[2] + c[3];
  part[tid] = s;
  __syncthreads();
  for (int d = 1; d < 256; d <<= 1) {
    int x = (tid >= d) ? part[tid - d] : 0;
    __syncthreads();
    part[tid] += x;
    __syncthreads();
  }
  int run = bsum[b] + ((tid > 0) ? part[tid - 1] : 0);
#pragma unroll
  for (int q = 0; q < 4; ++q) {
    if (idx + q < SCAN_N) {
      off[idx + q] = run;
      cur[idx + q] = run;
      run += c[q];
    }
  }
  if (b == 0 && tid == 0) off[SCAN_N] = 2 * NE;  // total is structural
}

__global__ void k_fill(const int* __restrict__ from, const int* __restrict__ to,
                       int* __restrict__ cur, int* __restrict__ nbr) {
  int e = blockIdx.x * 256 + threadIdx.x;
  if (e < NE) {
    int f = from[e], t = to[e];
    nbr[atomicAdd(cur + t, 1)] = f;
    nbr[atomicAdd(cur + NN + f, 1)] = t;
  }
}

// ---------------- K1: MFMA projection, T[n][1024] row-major fp16 ----------------
__global__ __launch_bounds__(256) void k_proj(const u16* __restrict__ nsf,
                                              const u16* __restrict__ Wc16,
                                              const float* __restrict__ biascat,
                                              u16* __restrict__ T) {
  const int w = threadIdx.x >> 6, lane = threadIdx.x & 63;
  const int mt = blockIdx.x;
  f4v acc[16];
#pragma unroll
  for (int t = 0; t < 16; ++t) acc[t] = (f4v){0.f, 0.f, 0.f, 0.f};

#pragma unroll
  for (int kt = 0; kt < 4; ++kt) {
    h8 a = *(const h8*)(nsf + ((size_t)mt * 4 + kt) * 512 + lane * 8);
#pragma unroll
    for (int t = 0; t < 16; ++t) {
      int nt = w * 16 + t;
      h8 b = *(const h8*)(Wc16 + ((size_t)nt * 4 + kt) * 512 + lane * 8);
      acc[t] = __builtin_amdgcn_mfma_f32_16x16x32_f16(a, b, acc[t], 0, 0, 0);
    }
  }
  const int c0 = lane & 15, rB = (lane >> 4) * 4;
#pragma unroll
  for (int t = 0; t < 16; ++t) {
    int col = (w * 16 + t) * 16 + c0;
    float bias = biascat[col];
#pragma unroll
    for (int reg = 0; reg < 4; ++reg) {
      int row = mt * 16 + rB + reg;
      T[(size_t)row * 1024 + col] = f2h(acc[t][reg] + bias);
    }
  }
}

// ---------------- K2: CSR gather -> S in A-fragment layout (fp16) ----------------
__global__ __launch_bounds__(256) void k_gather(const u16* __restrict__ T,
                                                const int* __restrict__ nbr,
                                                const int* __restrict__ off,
                                                u16* __restrict__ Sf) {
  const int lane = threadIdx.x & 63;
  const int n = blockIdx.x * 4 + (threadIdx.x >> 6);
  if (n >= NN) return;
  const u16* Tn = T + (size_t)n * 1024;
  const int mt = n >> 4, r = n & 15;
  const int g = (lane & 7) >> 1, j0 = (lane & 1) * 4;
  const int laneF = r + g * 16;

  for (int dir = 0; dir < 2; ++dir) {
    const int invofs = dir ? 256 : 512;
    const int gofs = dir ? 768 : 0;
    float4 inv = load4h(Tn + invofs + lane * 4);
    const int s = off[dir * NN + n];
    const int e = off[dir * NN + n + 1];
    float4 a0 = make_float4(0.f, 0.f, 0.f, 0.f);
    float4 a1 = make_float4(0.f, 0.f, 0.f, 0.f);
    float4 a2 = make_float4(0.f, 0.f, 0.f, 0.f);
    float4 a3 = make_float4(0.f, 0.f, 0.f, 0.f);
    for (int i = s; i < e; i += 64) {
      int nb = (i + lane < e) ? nbr[i + lane] : 0;
      int cnt = min(64, e - i);
      int k = 0;
      for (; k + 3 < cnt; k += 4) {
        int f0 = __shfl(nb, k);
        int f1 = __shfl(nb, k + 1);
        int f2 = __shfl(nb, k + 2);
        int f3 = __shfl(nb, k + 3);
        float4 v0 = load4h(T + (size_t)f0 * 1024 + gofs + lane * 4);
        float4 v1 = load4h(T + (size_t)f1 * 1024 + gofs + lane * 4);
        float4 v2 = load4h(T + (size_t)f2 * 1024 + gofs + lane * 4);
        float4 v3 = load4h(T + (size_t)f3 * 1024 + gofs + lane * 4);
        a0.x += fmaxf(inv.x + v0.x, 0.f); a1.x += fmaxf(inv.x + v1.x, 0.f);
        a0.y += fmaxf(inv.y + v0.y, 0.f); a1.y += fmaxf(inv.y + v1.y, 0.f);
        a0.z += fmaxf(inv.z + v0.z, 0.f); a1.z += fmaxf(inv.z + v1.z, 0.f);
        a0.w += fmaxf(inv.w + v0.w, 0.f); a1.w += fmaxf(inv.w + v1.w, 0.f);
        a2.x += fmaxf(inv.x + v2.x, 0.f); a3.x += fmaxf(inv.x + v3.x, 0.f);
        a2.y += fmaxf(inv.y + v2.y, 0.f); a3.y += fmaxf(inv.y + v3.y, 0.f);
        a2.z += fmaxf(inv.z + v2.z, 0.f); a3.z += fmaxf(inv.z + v3.z, 0.f);
        a2.w += fmaxf(inv.w + v2.w, 0.f); a3.w += fmaxf(inv.w + v3.w, 0.f);
      }
      for (; k < cnt; ++k) {
        int f0 = __shfl(nb, k);
        float4 v0 = load4h(T + (size_t)f0 * 1024 + gofs + lane * 4);
        a0.x += fmaxf(inv.x + v0.x, 0.f);
        a0.y += fmaxf(inv.y + v0.y, 0.f);
        a0.z += fmaxf(inv.z + v0.z, 0.f);
        a0.w += fmaxf(inv.w + v0.w, 0.f);
      }
    }
    a0.x += a1.x + a2.x + a3.x;
    a0.y += a1.y + a2.y + a3.y;
    a0.z += a1.z + a2.z + a3.z;
    a0.w += a1.w + a2.w + a3.w;
    int kt = dir * 8 + (lane >> 3);
    u16 hv[4] = {f2h(a0.x), f2h(a0.y), f2h(a0.z), f2h(a0.w)};
    *(ushort4*)(Sf + ((size_t)mt * 16 + kt) * 512 + laneF * 8 + j0) = *(const ushort4*)hv;
  }
}

// ---------------- K3: MFMA GRU, LDS-free ----------------
__global__ __launch_bounds__(256) void k_gru(const u16* __restrict__ Sf,
                                             const u16* __restrict__ nsf,
                                             const u16* __restrict__ G16,
                                             const u16* __restrict__ Wh16,
                                             const float* __restrict__ ns,
                                             const float* __restrict__ b_ih,
                                             const float* __restrict__ b_hh,
                                             const float* __restrict__ vf,
                                             const float* __restrict__ vr,
                                             const int* __restrict__ off,
                                             float* __restrict__ out) {
  const int w = threadIdx.x >> 6, lane = threadIdx.x & 63;
  const int mt0 = blockIdx.x * 2;
  const bool v0 = (mt0 * 16) < NN;
  const bool v1 = ((mt0 + 1) * 16) < NN;
  const h8 hz = {(_Float16)0.f, (_Float16)0.f, (_Float16)0.f, (_Float16)0.f,
                 (_Float16)0.f, (_Float16)0.f, (_Float16)0.f, (_Float16)0.f};

  f4v gh[2][2][3], gi[2][2][3];
#pragma unroll
  for (int a = 0; a < 2; ++a)
#pragma unroll
    for (int p = 0; p < 2; ++p)
#pragma unroll
      for (int g = 0; g < 3; ++g) {
        gh[a][p][g] = (f4v){0.f, 0.f, 0.f, 0.f};
        gi[a][p][g] = (f4v){0.f, 0.f, 0.f, 0.f};
      }

  // step A: gh = ns @ W_hh.T (K=128)
#pragma unroll
  for (int kt = 0; kt < 4; ++kt) {
    h8 a0 = v0 ? *(const h8*)(nsf + ((size_t)mt0 * 4 + kt) * 512 + lane * 8) : hz;
    h8 a1 = v1 ? *(const h8*)(nsf + ((size_t)(mt0 + 1) * 4 + kt) * 512 + lane * 8) : hz;
#pragma unroll
    for (int g = 0; g < 3; ++g)
#pragma unroll
      for (int p = 0; p < 2; ++p) {
        int nt = 2 * w + p + 8 * g;
        h8 b = *(const h8*)(Wh16 + ((size_t)nt * 4 + kt) * 512 + lane * 8);
        gh[0][p][g] = __builtin_amdgcn_mfma_f32_16x16x32_f16(a0, b, gh[0][p][g], 0, 0, 0);
        gh[1][p][g] = __builtin_amdgcn_mfma_f32_16x16x32_f16(a1, b, gh[1][p][g], 0, 0, 0);
      }
  }

  // step B: gi = S @ Gcat.T (K=512)
#pragma unroll
  for (int kt = 0; kt < 16; ++kt) {
    h8 a0 = v0 ? *(const h8*)(Sf + ((size_t)mt0 * 16 + kt) * 512 + lane * 8) : hz;
    h8 a1 = v1 ? *(const h8*)(Sf + ((size_t)(mt0 + 1) * 16 + kt) * 512 + lane * 8) : hz;
#pragma unroll
    for (int g = 0; g < 3; ++g)
#pragma unroll
      for (int p = 0; p < 2; ++p) {
        int nt = 2 * w + p + 8 * g;
        h8 b = *(const h8*)(G16 + ((size_t)nt * 16 + kt) * 512 + lane * 8);
        gi[0][p][g] = __builtin_amdgcn_mfma_f32_16x16x32_f16(a0, b, gi[0][p][g], 0, 0, 0);
        gi[1][p][g] = __builtin_amdgcn_mfma_f32_16x16x32_f16(a1, b, gi[1][p][g], 0, 0, 0);
      }
  }

  // epilogue
  const int c0 = lane & 15, rB = (lane >> 4) * 4;
#pragma unroll
  for (int a = 0; a < 2; ++a) {
    if (!(a ? v1 : v0)) continue;
    const int mt = mt0 + a;
    float idg[4], odg[4];
#pragma unroll
    for (int reg = 0; reg < 4; ++reg) {
      int row = mt * 16 + rB + reg;
      idg[reg] = (float)(off[row + 1] - off[row]);
      odg[reg] = (float)(off[NN + row + 1] - off[NN + row]);
    }
#pragma unroll
    for (int p = 0; p < 2; ++p) {
      int d = (2 * w + p) * 16 + c0;
      float vf0 = vf[d], vf1 = vf[128 + d], vf2 = vf[256 + d];
      float vr0 = vr[d], vr1 = vr[128 + d], vr2 = vr[256 + d];
      float bi0 = b_ih[d], bi1 = b_ih[128 + d], bi2 = b_ih[256 + d];
      float bh0 = b_hh[d], bh1 = b_hh[128 + d], bh2 = b_hh[256 + d];
#pragma unroll
      for (int reg = 0; reg < 4; ++reg) {
        int row = mt * 16 + rB + reg;
        float gr = gi[a][p][0][reg] + idg[reg] * vf0 + odg[reg] * vr0 + bi0;
        float gz = gi[a][p][1][reg] + idg[reg] * vf1 + odg[reg] * vr1 + bi1;
        float gn = gi[a][p][2][reg] + idg[reg] * vf2 + odg[reg] * vr2 + bi2;
        float hr = gh[a][p][0][reg] + bh0;
        float hzv = gh[a][p][1][reg] + bh1;
        float hn = gh[a][p][2][reg] + bh2;
        float rg = 1.f / (1.f + __expf(-(gr + hr)));
        float zg = 1.f / (1.f + __expf(-(gz + hzv)));
        float ng = tanhf(gn + rg * hn);
        float h = ns[(size_t)row * 128 + d];
        out[(size_t)row * 128 + d] = (1.f - zg) * ng + zg * h;
      }
    }
  }
}

// ---------------- launch ----------------
extern "C" void kernel_launch(void* const* d_in, const int* in_sizes, int n_in,
                              void* d_out, int out_size, void* d_ws, size_t ws_size,
                              hipStream_t stream) {
  const float* ns   = (const float*)d_in[0];
  const int* from   = (const int*)d_in[1];
  const int* to     = (const int*)d_in[2];
  const float* Wf1  = (const float*)d_in[3];
  const float* bf1  = (const float*)d_in[4];
  const float* Wf2  = (const float*)d_in[5];
  const float* bf2  = (const float*)d_in[6];
  const float* Wr1  = (const float*)d_in[7];
  const float* br1  = (const float*)d_in[8];
  const float* Wr2  = (const float*)d_in[9];
  const float* br2  = (const float*)d_in[10];
  const float* W_ih = (const float*)d_in[11];
  const float* W_hh = (const float*)d_in[12];
  const float* b_ih = (const float*)d_in[13];
  const float* b_hh = (const float*)d_in[14];
  float* out = (float*)d_out;

  // workspace layout (256B aligned)
  char* w = (char*)d_ws;
  u16*   Wc16    = (u16*)(w + 0);            // 262144
  float* biascat = (float*)(w + 262144);     // 4096
  u16*   G16     = (u16*)(w + 266240);       // 393216
  u16*   Wh16    = (u16*)(w + 659456);       // 98304
  float* vf      = (float*)(w + 757760);     // 1536
  float* vr      = (float*)(w + 759296);     // 1536
  int*   cnt     = (int*)(w + 760832);       // 400128
  int*   off     = (int*)(w + 1160960);      // 400128
  int*   cur     = (int*)(w + 1561088);      // 400128
  int*   bsum    = (int*)(w + 1961216);      // 512
  int*   nbr     = (int*)(w + 1961728);      // 4096000
  u16*   nsf     = (u16*)(w + 6057728);      // 12800000
  u16*   T       = (u16*)(w + 18857728);     // 102400000
  u16*   Sf      = (u16*)(w + 121257728);    // 51200000
  // total 172457728 bytes

  hipMemsetAsync(cnt, 0, 400000, stream);

  k_wcat<<<1024, 128, 0, stream>>>(Wf1, bf1, Wr1, br1, Wc16, biascat);
  k_gcat<<<768, 256, 0, stream>>>(W_ih, Wf2, Wr2, G16);
  k_whh<<<384, 128, 0, stream>>>(W_hh, Wh16);
  k_vbias<<<3, 128, 0, stream>>>(W_ih, bf2, br2, vf, vr);
  k_nsh<<<3125, 256, 0, stream>>>(ns, nsf);

  k_hist<<<(NE + 255) / 256, 256, 0, stream>>>(from, to, cnt);
  k_scanA<<<SCAN_BLOCKS, 256, 0, stream>>>(cnt, bsum);
  k_scanB<<<1, 128, 0, stream>>>(bsum);
  k_scanC<<<SCAN_BLOCKS, 256, 0, stream>>>(cnt, bsum, off, cur);
  k_fill<<<(NE + 255) / 256, 256, 0, stream>>>(from, to, cur, nbr);

  k_proj<<<3125, 256, 0, stream>>>(nsf, Wc16, biascat, T);
  k_gather<<<12500, 256, 0, stream>>>(T, nbr, off, Sf);
  k_gru<<<1563, 256, 0, stream>>>(Sf, nsf, G16, Wh16, ns, b_ih, b_hh, vf, vr, off, out);
}

// Round 6
// 363.866 us; speedup vs baseline: 12.1547x; 1.1441x over previous
//
#include <hip/hip_runtime.h>
#include <stdint.h>

// GraphPropLayer on MI355X — round 6: occupancy/latency attack on the three big
// kernels. k_gru: 1 mt + 3 nt-tiles per wave (acc 96->24 regs, grid 6250).
// k_proj: 4mt x 4nt per wave (B-traffic /4, grid dim3(782,4)).
// k_gather: one wave per (node,dir) (grid 25000).
//
// Fragment layout (v_mfma_f32_16x16x32_f16):
//   A (16m x 32k): lane = row + 16*((k%32)/8), elem j = k%8
//   B (32k x 16n): lane = col + 16*((k%32)/8), elem j = k%8
//   C/D: col = lane&15, row = (lane>>4)*4 + reg
// Tile = 512 halfs (1 KB); buffers indexed [(mt_or_nt * KT + kt)*512 + lane*8 + j].

#define NN 50000
#define NE 512000
#define SCAN_N (2 * NN)
#define SCAN_BLOCKS ((SCAN_N + 1023) / 1024)  // 98

typedef unsigned short u16;
typedef unsigned int u32;
using h8  = __attribute__((ext_vector_type(8))) _Float16;
using f4v = __attribute__((ext_vector_type(4))) float;

__device__ __forceinline__ float h2f(u16 u) {
  _Float16 h; __builtin_memcpy(&h, &u, 2); return (float)h;
}
__device__ __forceinline__ u16 f2h(float f) {
  _Float16 h = (_Float16)f; u16 u; __builtin_memcpy(&u, &h, 2); return u;
}
__device__ __forceinline__ float4 load4h(const u16* p) {
  ushort4 u = *(const ushort4*)p;
  return make_float4(h2f(u.x), h2f(u.y), h2f(u.z), h2f(u.w));
}

// ---------------- prep kernels (tiny) ----------------

// Wcat fragment (64 nt x 4 kt). T col c semantics:
// [0,256): Wf1[:,0:128](+bf1) | [256,512): Wr1[:,128:256] | [512,768): Wf1[:,128:256]
// | [768,1024): Wr1[:,0:128](+br1)
__global__ void k_wcat(const float* __restrict__ Wf1, const float* __restrict__ bf1,
                       const float* __restrict__ Wr1, const float* __restrict__ br1,
                       u16* __restrict__ Wc16, float* __restrict__ biascat) {
  int c = blockIdx.x;
  int k = threadIdx.x;
  const float* src;
  if (c < 256)      src = Wf1 + (size_t)c * 256;
  else if (c < 512) src = Wr1 + (size_t)(c - 256) * 256 + 128;
  else if (c < 768) src = Wf1 + (size_t)(c - 512) * 256 + 128;
  else              src = Wr1 + (size_t)(c - 768) * 256;
  float v = src[k];
  int nt = c >> 4, kt = k >> 5, g = (k & 31) >> 3, j = k & 7;
  int lane = (c & 15) + g * 16;
  Wc16[((size_t)nt * 4 + kt) * 512 + lane * 8 + j] = f2h(v);
  if (k == 0) biascat[c] = (c < 256) ? bf1[c] : ((c >= 768) ? br1[c - 768] : 0.f);
}

// Gcat fragment (24 nt x 16 kt)
__global__ void k_gcat(const float* __restrict__ W_ih, const float* __restrict__ Wf2,
                       const float* __restrict__ Wr2, u16* __restrict__ G16) {
  int b = blockIdx.x;
  int c = b % 384, w = b / 384;
  const float* W2 = w ? Wr2 : Wf2;
  int k = threadIdx.x;
  float acc = 0.f;
  for (int o = 0; o < 256; ++o)
    acc = fmaf(W_ih[(size_t)c * 256 + o], W2[(size_t)o * 256 + k], acc);
  int kg = w * 256 + k;
  int nt = c >> 4, kt = kg >> 5, g = (kg & 31) >> 3, j = kg & 7;
  int lane = (c & 15) + g * 16;
  G16[((size_t)nt * 16 + kt) * 512 + lane * 8 + j] = f2h(acc);
}

// W_hh fragment (24 nt x 4 kt)
__global__ void k_whh(const float* __restrict__ W_hh, u16* __restrict__ Wh16) {
  int c = blockIdx.x, k = threadIdx.x;
  float v = W_hh[(size_t)c * 128 + k];
  int nt = c >> 4, kt = k >> 5, g = (k & 31) >> 3, j = k & 7;
  int lane = (c & 15) + g * 16;
  Wh16[((size_t)nt * 4 + kt) * 512 + lane * 8 + j] = f2h(v);
}

__global__ void k_vbias(const float* __restrict__ W_ih, const float* __restrict__ bf2,
                        const float* __restrict__ br2, float* __restrict__ vf,
                        float* __restrict__ vr) {
  int c = blockIdx.x * blockDim.x + threadIdx.x;
  if (c >= 384) return;
  float a = 0.f, b = 0.f;
  for (int o = 0; o < 256; ++o) {
    float w = W_ih[(size_t)c * 256 + o];
    a = fmaf(w, bf2[o], a);
    b = fmaf(w, br2[o], b);
  }
  vf[c] = a; vr[c] = b;
}

// ns -> fp16 A-fragment (3125 mt x 4 kt)
__global__ void k_nsh(const float* __restrict__ ns, u16* __restrict__ nsf) {
  int t = blockIdx.x * 256 + threadIdx.x;
  int n = t >> 4, kk8 = t & 15;
  float4 v0 = *(const float4*)(ns + (size_t)n * 128 + kk8 * 8);
  float4 v1 = *(const float4*)(ns + (size_t)n * 128 + kk8 * 8 + 4);
  u16 hv[8] = {f2h(v0.x), f2h(v0.y), f2h(v0.z), f2h(v0.w),
               f2h(v1.x), f2h(v1.y), f2h(v1.z), f2h(v1.w)};
  int mt = n >> 4, r = n & 15, kt = kk8 >> 2, g = kk8 & 3;
  int lane = r + g * 16;
  *(uint4*)(nsf + ((size_t)mt * 4 + kt) * 512 + lane * 8) = *(const uint4*)hv;
}

// ---------------- CSR build ----------------
__global__ void k_hist(const int* __restrict__ from, const int* __restrict__ to,
                       int* __restrict__ cnt) {
  int e = blockIdx.x * 256 + threadIdx.x;
  if (e < NE) {
    atomicAdd(cnt + to[e], 1);
    atomicAdd(cnt + NN + from[e], 1);
  }
}

__global__ __launch_bounds__(256) void k_scanA(const int* __restrict__ cnt,
                                               int* __restrict__ bsum) {
  __shared__ int part[256];
  int b = blockIdx.x, tid = threadIdx.x;
  int idx = b * 1024 + tid * 4;
  int s = 0;
  if (idx + 3 < SCAN_N) {
    int4 v = *(const int4*)(cnt + idx);
    s = v.x + v.y + v.z + v.w;
  } else {
    for (int q = 0; q < 4; ++q)
      if (idx + q < SCAN_N) s += cnt[idx + q];
  }
  part[tid] = s;
  __syncthreads();
  for (int d = 128; d > 0; d >>= 1) {
    if (tid < d) part[tid] += part[tid + d];
    __syncthreads();
  }
  if (tid == 0) bsum[b] = part[0];
}

__global__ __launch_bounds__(128) void k_scanB(int* __restrict__ bsum) {
  __shared__ int part[128];
  int tid = threadIdx.x;
  int v = (tid < SCAN_BLOCKS) ? bsum[tid] : 0;
  part[tid] = v;
  __syncthreads();
  for (int d = 1; d < 128; d <<= 1) {
    int x = (tid >= d) ? part[tid - d] : 0;
    __syncthreads();
    part[tid] += x;
    __syncthreads();
  }
  if (tid < SCAN_BLOCKS) bsum[tid] = (tid > 0) ? part[tid - 1] : 0;
}

__global__ __launch_bounds__(256) void k_scanC(const int* __restrict__ cnt,
                                               const int* __restrict__ bsum,
                                               int* __restrict__ off,
                                               int* __restrict__ cur) {
  __shared__ int part[256];
  int b = blockIdx.x, tid = threadIdx.x;
  int idx = b * 1024 + tid * 4;
  int c[4] = {0, 0, 0, 0};
  if (idx + 3 < SCAN_N) {
    int4 v = *(const int4*)(cnt + idx);
    c[0] = v.x; c[1] = v.y; c[2] = v.z; c[3] = v.w;
  } else {
    for (int q = 0; q < 4; ++q)
      if (idx + q < SCAN_N) c[q] = cnt[idx + q];
  }
  int s = c[0] + c[1] + c[2] + c[3];
  part[tid] = s;
  __syncthreads();
  for (int d = 1; d < 256; d <<= 1) {
    int x = (tid >= d) ? part[tid - d] : 0;
    __syncthreads();
    part[tid] += x;
    __syncthreads();
  }
  int run = bsum[b] + ((tid > 0) ? part[tid - 1] : 0);
#pragma unroll
  for (int q = 0; q < 4; ++q) {
    if (idx + q < SCAN_N) {
      off[idx + q] = run;
      cur[idx + q] = run;
      run += c[q];
    }
  }
  if (b == 0 && tid == 0) off[SCAN_N] = 2 * NE;
}

__global__ void k_fill(const int* __restrict__ from, const int* __restrict__ to,
                       int* __restrict__ cur, int* __restrict__ nbr) {
  int e = blockIdx.x * 256 + threadIdx.x;
  if (e < NE) {
    int f = from[e], t = to[e];
    nbr[atomicAdd(cur + t, 1)] = f;
    nbr[atomicAdd(cur + NN + f, 1)] = t;
  }
}

// ---------------- K1: MFMA projection ----------------
// grid dim3(782, 4). Block: 4 mt (shared by all waves); wave w: 4 nt.
// nt = blockIdx.y*16 + w*4 + n. B fetched once per wave (16 KB), A reused 4x.
__global__ __launch_bounds__(256) void k_proj(const u16* __restrict__ nsf,
                                              const u16* __restrict__ Wc16,
                                              const float* __restrict__ biascat,
                                              u16* __restrict__ T) {
  const int w = threadIdx.x >> 6, lane = threadIdx.x & 63;
  const int mt0 = blockIdx.x * 4;
  const int nt0 = blockIdx.y * 16 + w * 4;
  const h8 hzv = {(_Float16)0.f, (_Float16)0.f, (_Float16)0.f, (_Float16)0.f,
                  (_Float16)0.f, (_Float16)0.f, (_Float16)0.f, (_Float16)0.f};
  f4v acc[4][4];
#pragma unroll
  for (int m = 0; m < 4; ++m)
#pragma unroll
    for (int n = 0; n < 4; ++n) acc[m][n] = (f4v){0.f, 0.f, 0.f, 0.f};

#pragma unroll
  for (int kt = 0; kt < 4; ++kt) {
    h8 a[4], b[4];
#pragma unroll
    for (int m = 0; m < 4; ++m) {
      int mt = mt0 + m;
      a[m] = (mt < 3125) ? *(const h8*)(nsf + ((size_t)mt * 4 + kt) * 512 + lane * 8) : hzv;
    }
#pragma unroll
    for (int n = 0; n < 4; ++n)
      b[n] = *(const h8*)(Wc16 + ((size_t)(nt0 + n) * 4 + kt) * 512 + lane * 8);
#pragma unroll
    for (int m = 0; m < 4; ++m)
#pragma unroll
      for (int n = 0; n < 4; ++n)
        acc[m][n] = __builtin_amdgcn_mfma_f32_16x16x32_f16(a[m], b[n], acc[m][n], 0, 0, 0);
  }

  const int c0 = lane & 15, rB = (lane >> 4) * 4;
#pragma unroll
  for (int m = 0; m < 4; ++m) {
    int mt = mt0 + m;
    if (mt >= 3125) continue;
#pragma unroll
    for (int n = 0; n < 4; ++n) {
      int col = (nt0 + n) * 16 + c0;
      float bias = biascat[col];
#pragma unroll
      for (int reg = 0; reg < 4; ++reg) {
        int row = mt * 16 + rB + reg;
        T[(size_t)row * 1024 + col] = f2h(acc[m][n][reg] + bias);
      }
    }
  }
}

// ---------------- K2: CSR gather -> S in A-fragment layout (fp16) ----------------
// One wave per (node, dir). grid 25000 x 256 thr = 100000 wave-slots exactly.
__global__ __launch_bounds__(256) void k_gather(const u16* __restrict__ T,
                                                const int* __restrict__ nbr,
                                                const int* __restrict__ off,
                                                u16* __restrict__ Sf) {
  const int lane = threadIdx.x & 63;
  const int gid = blockIdx.x * 4 + (threadIdx.x >> 6);
  const int n = gid >> 1, dir = gid & 1;
  const u16* Tn = T + (size_t)n * 1024;
  const int mt = n >> 4, r = n & 15;
  const int g = (lane & 7) >> 1, j0 = (lane & 1) * 4;
  const int laneF = r + g * 16;

  const int invofs = dir ? 256 : 512;
  const int gofs = dir ? 768 : 0;
  float4 inv = load4h(Tn + invofs + lane * 4);
  const int s = off[dir * NN + n];
  const int e = off[dir * NN + n + 1];
  float4 a0 = make_float4(0.f, 0.f, 0.f, 0.f);
  float4 a1 = make_float4(0.f, 0.f, 0.f, 0.f);
  float4 a2 = make_float4(0.f, 0.f, 0.f, 0.f);
  float4 a3 = make_float4(0.f, 0.f, 0.f, 0.f);
  for (int i = s; i < e; i += 64) {
    int nb = (i + lane < e) ? nbr[i + lane] : 0;
    int cnt = min(64, e - i);
    int k = 0;
    for (; k + 3 < cnt; k += 4) {
      int f0 = __shfl(nb, k);
      int f1 = __shfl(nb, k + 1);
      int f2 = __shfl(nb, k + 2);
      int f3 = __shfl(nb, k + 3);
      float4 v0 = load4h(T + (size_t)f0 * 1024 + gofs + lane * 4);
      float4 v1 = load4h(T + (size_t)f1 * 1024 + gofs + lane * 4);
      float4 v2 = load4h(T + (size_t)f2 * 1024 + gofs + lane * 4);
      float4 v3 = load4h(T + (size_t)f3 * 1024 + gofs + lane * 4);
      a0.x += fmaxf(inv.x + v0.x, 0.f); a1.x += fmaxf(inv.x + v1.x, 0.f);
      a0.y += fmaxf(inv.y + v0.y, 0.f); a1.y += fmaxf(inv.y + v1.y, 0.f);
      a0.z += fmaxf(inv.z + v0.z, 0.f); a1.z += fmaxf(inv.z + v1.z, 0.f);
      a0.w += fmaxf(inv.w + v0.w, 0.f); a1.w += fmaxf(inv.w + v1.w, 0.f);
      a2.x += fmaxf(inv.x + v2.x, 0.f); a3.x += fmaxf(inv.x + v3.x, 0.f);
      a2.y += fmaxf(inv.y + v2.y, 0.f); a3.y += fmaxf(inv.y + v3.y, 0.f);
      a2.z += fmaxf(inv.z + v2.z, 0.f); a3.z += fmaxf(inv.z + v3.z, 0.f);
      a2.w += fmaxf(inv.w + v2.w, 0.f); a3.w += fmaxf(inv.w + v3.w, 0.f);
    }
    for (; k < cnt; ++k) {
      int f0 = __shfl(nb, k);
      float4 v0 = load4h(T + (size_t)f0 * 1024 + gofs + lane * 4);
      a0.x += fmaxf(inv.x + v0.x, 0.f);
      a0.y += fmaxf(inv.y + v0.y, 0.f);
      a0.z += fmaxf(inv.z + v0.z, 0.f);
      a0.w += fmaxf(inv.w + v0.w, 0.f);
    }
  }
  a0.x += a1.x + a2.x + a3.x;
  a0.y += a1.y + a2.y + a3.y;
  a0.z += a1.z + a2.z + a3.z;
  a0.w += a1.w + a2.w + a3.w;
  int kt = dir * 8 + (lane >> 3);
  u16 hv[4] = {f2h(a0.x), f2h(a0.y), f2h(a0.z), f2h(a0.w)};
  *(ushort4*)(Sf + ((size_t)mt * 16 + kt) * 512 + laneF * 8 + j0) = *(const ushort4*)hv;
}

// ---------------- K3: MFMA GRU, LDS-free, 1 mt + 3 nt per wave ----------------
// grid 6250: block b -> mt = b>>1, half = b&1; wave w: base = half*4+w (0..7),
// nt(g) = base + 8g. Gate triplet (d, 128+d, 256+d) lane-local, d = base*16+c0.
__global__ __launch_bounds__(256) void k_gru(const u16* __restrict__ Sf,
                                             const u16* __restrict__ nsf,
                                             const u16* __restrict__ G16,
                                             const u16* __restrict__ Wh16,
                                             const float* __restrict__ ns,
                                             const float* __restrict__ b_ih,
                                             const float* __restrict__ b_hh,
                                             const float* __restrict__ vf,
                                             const float* __restrict__ vr,
                                             const int* __restrict__ off,
                                             float* __restrict__ out) {
  const int w = threadIdx.x >> 6, lane = threadIdx.x & 63;
  const int mt = blockIdx.x >> 1, half = blockIdx.x & 1;
  const int base = half * 4 + w;

  f4v gh[3], gi[3];
#pragma unroll
  for (int g = 0; g < 3; ++g) {
    gh[g] = (f4v){0.f, 0.f, 0.f, 0.f};
    gi[g] = (f4v){0.f, 0.f, 0.f, 0.f};
  }

  // step A: gh = ns @ W_hh.T (K=128)
#pragma unroll
  for (int kt = 0; kt < 4; ++kt) {
    h8 a = *(const h8*)(nsf + ((size_t)mt * 4 + kt) * 512 + lane * 8);
#pragma unroll
    for (int g = 0; g < 3; ++g) {
      h8 b = *(const h8*)(Wh16 + ((size_t)(base + 8 * g) * 4 + kt) * 512 + lane * 8);
      gh[g] = __builtin_amdgcn_mfma_f32_16x16x32_f16(a, b, gh[g], 0, 0, 0);
    }
  }

  // step B: gi = S @ Gcat.T (K=512)
#pragma unroll
  for (int kt = 0; kt < 16; ++kt) {
    h8 a = *(const h8*)(Sf + ((size_t)mt * 16 + kt) * 512 + lane * 8);
#pragma unroll
    for (int g = 0; g < 3; ++g) {
      h8 b = *(const h8*)(G16 + ((size_t)(base + 8 * g) * 16 + kt) * 512 + lane * 8);
      gi[g] = __builtin_amdgcn_mfma_f32_16x16x32_f16(a, b, gi[g], 0, 0, 0);
    }
  }

  // epilogue
  const int c0 = lane & 15, rB = (lane >> 4) * 4;
  const int d = base * 16 + c0;
  const float vf0 = vf[d], vf1 = vf[128 + d], vf2 = vf[256 + d];
  const float vr0 = vr[d], vr1 = vr[128 + d], vr2 = vr[256 + d];
  const float bi0 = b_ih[d], bi1 = b_ih[128 + d], bi2 = b_ih[256 + d];
  const float bh0 = b_hh[d], bh1 = b_hh[128 + d], bh2 = b_hh[256 + d];
#pragma unroll
  for (int reg = 0; reg < 4; ++reg) {
    int row = mt * 16 + rB + reg;
    float idg = (float)(off[row + 1] - off[row]);
    float odg = (float)(off[NN + row + 1] - off[NN + row]);
    float gr = gi[0][reg] + idg * vf0 + odg * vr0 + bi0;
    float gz = gi[1][reg] + idg * vf1 + odg * vr1 + bi1;
    float gn = gi[2][reg] + idg * vf2 + odg * vr2 + bi2;
    float hr = gh[0][reg] + bh0;
    float hzv = gh[1][reg] + bh1;
    float hn = gh[2][reg] + bh2;
    float rg = 1.f / (1.f + __expf(-(gr + hr)));
    float zg = 1.f / (1.f + __expf(-(gz + hzv)));
    float ng = tanhf(gn + rg * hn);
    float h = ns[(size_t)row * 128 + d];
    out[(size_t)row * 128 + d] = (1.f - zg) * ng + zg * h;
  }
}

// ---------------- launch ----------------
extern "C" void kernel_launch(void* const* d_in, const int* in_sizes, int n_in,
                              void* d_out, int out_size, void* d_ws, size_t ws_size,
                              hipStream_t stream) {
  const float* ns   = (const float*)d_in[0];
  const int* from   = (const int*)d_in[1];
  const int* to     = (const int*)d_in[2];
  const float* Wf1  = (const float*)d_in[3];
  const float* bf1  = (const float*)d_in[4];
  const float* Wf2  = (const float*)d_in[5];
  const float* bf2  = (const float*)d_in[6];
  const float* Wr1  = (const float*)d_in[7];
  const float* br1  = (const float*)d_in[8];
  const float* Wr2  = (const float*)d_in[9];
  const float* br2  = (const float*)d_in[10];
  const float* W_ih = (const float*)d_in[11];
  const float* W_hh = (const float*)d_in[12];
  const float* b_ih = (const float*)d_in[13];
  const float* b_hh = (const float*)d_in[14];
  float* out = (float*)d_out;

  // workspace layout (256B aligned)
  char* w = (char*)d_ws;
  u16*   Wc16    = (u16*)(w + 0);            // 262144
  float* biascat = (float*)(w + 262144);     // 4096
  u16*   G16     = (u16*)(w + 266240);       // 393216
  u16*   Wh16    = (u16*)(w + 659456);       // 98304
  float* vf      = (float*)(w + 757760);     // 1536
  float* vr      = (float*)(w + 759296);     // 1536
  int*   cnt     = (int*)(w + 760832);       // 400128
  int*   off     = (int*)(w + 1160960);      // 400128
  int*   cur     = (int*)(w + 1561088);      // 400128
  int*   bsum    = (int*)(w + 1961216);      // 512
  int*   nbr     = (int*)(w + 1961728);      // 4096000
  u16*   nsf     = (u16*)(w + 6057728);      // 12800000
  u16*   T       = (u16*)(w + 18857728);     // 102400000
  u16*   Sf      = (u16*)(w + 121257728);    // 51200000
  // total 172457728 bytes

  hipMemsetAsync(cnt, 0, 400000, stream);

  k_wcat<<<1024, 128, 0, stream>>>(Wf1, bf1, Wr1, br1, Wc16, biascat);
  k_gcat<<<768, 256, 0, stream>>>(W_ih, Wf2, Wr2, G16);
  k_whh<<<384, 128, 0, stream>>>(W_hh, Wh16);
  k_vbias<<<3, 128, 0, stream>>>(W_ih, bf2, br2, vf, vr);
  k_nsh<<<3125, 256, 0, stream>>>(ns, nsf);

  k_hist<<<(NE + 255) / 256, 256, 0, stream>>>(from, to, cnt);
  k_scanA<<<SCAN_BLOCKS, 256, 0, stream>>>(cnt, bsum);
  k_scanB<<<1, 128, 0, stream>>>(bsum);
  k_scanC<<<SCAN_BLOCKS, 256, 0, stream>>>(cnt, bsum, off, cur);
  k_fill<<<(NE + 255) / 256, 256, 0, stream>>>(from, to, cur, nbr);

  k_proj<<<dim3(782, 4), 256, 0, stream>>>(nsf, Wc16, biascat, T);
  k_gather<<<25000, 256, 0, stream>>>(T, nbr, off, Sf);
  k_gru<<<6250, 256, 0, stream>>>(Sf, nsf, G16, Wh16, ns, b_ih, b_hh, vf, vr, off, out);
}

// Round 7
// 348.649 us; speedup vs baseline: 12.6852x; 1.0436x over previous
//
#include <hip/hip_runtime.h>
#include <stdint.h>

// GraphPropLayer on MI355X — round 7: gather inner loop -> packed-fp16 relu +
// 8-deep load batching; k_gru -> 2 mt per wave (halves G16 L2 re-reads).
//
// Fragment layout (v_mfma_f32_16x16x32_f16):
//   A (16m x 32k): lane = row + 16*((k%32)/8), elem j = k%8
//   B (32k x 16n): lane = col + 16*((k%32)/8), elem j = k%8
//   C/D: col = lane&15, row = (lane>>4)*4 + reg
// Tile = 512 halfs (1 KB); buffers indexed [(mt_or_nt * KT + kt)*512 + lane*8 + j].

#define NN 50000
#define NE 512000
#define SCAN_N (2 * NN)
#define SCAN_BLOCKS ((SCAN_N + 1023) / 1024)  // 98

typedef unsigned short u16;
typedef unsigned int u32;
using h2  = __attribute__((ext_vector_type(2))) _Float16;
using h4  = __attribute__((ext_vector_type(4))) _Float16;
using h8  = __attribute__((ext_vector_type(8))) _Float16;
using f4v = __attribute__((ext_vector_type(4))) float;

__device__ __forceinline__ float h2f(u16 u) {
  _Float16 h; __builtin_memcpy(&h, &u, 2); return (float)h;
}
__device__ __forceinline__ u16 f2h(float f) {
  _Float16 h = (_Float16)f; u16 u; __builtin_memcpy(&u, &h, 2); return u;
}

// ---------------- prep kernels (tiny) ----------------

// Wcat fragment (64 nt x 4 kt). T col c semantics:
// [0,256): Wf1[:,0:128](+bf1) | [256,512): Wr1[:,128:256] | [512,768): Wf1[:,128:256]
// | [768,1024): Wr1[:,0:128](+br1)
__global__ void k_wcat(const float* __restrict__ Wf1, const float* __restrict__ bf1,
                       const float* __restrict__ Wr1, const float* __restrict__ br1,
                       u16* __restrict__ Wc16, float* __restrict__ biascat) {
  int c = blockIdx.x;
  int k = threadIdx.x;
  const float* src;
  if (c < 256)      src = Wf1 + (size_t)c * 256;
  else if (c < 512) src = Wr1 + (size_t)(c - 256) * 256 + 128;
  else if (c < 768) src = Wf1 + (size_t)(c - 512) * 256 + 128;
  else              src = Wr1 + (size_t)(c - 768) * 256;
  float v = src[k];
  int nt = c >> 4, kt = k >> 5, g = (k & 31) >> 3, j = k & 7;
  int lane = (c & 15) + g * 16;
  Wc16[((size_t)nt * 4 + kt) * 512 + lane * 8 + j] = f2h(v);
  if (k == 0) biascat[c] = (c < 256) ? bf1[c] : ((c >= 768) ? br1[c - 768] : 0.f);
}

// Gcat fragment (24 nt x 16 kt)
__global__ void k_gcat(const float* __restrict__ W_ih, const float* __restrict__ Wf2,
                       const float* __restrict__ Wr2, u16* __restrict__ G16) {
  int b = blockIdx.x;
  int c = b % 384, w = b / 384;
  const float* W2 = w ? Wr2 : Wf2;
  int k = threadIdx.x;
  float acc = 0.f;
  for (int o = 0; o < 256; ++o)
    acc = fmaf(W_ih[(size_t)c * 256 + o], W2[(size_t)o * 256 + k], acc);
  int kg = w * 256 + k;
  int nt = c >> 4, kt = kg >> 5, g = (kg & 31) >> 3, j = kg & 7;
  int lane = (c & 15) + g * 16;
  G16[((size_t)nt * 16 + kt) * 512 + lane * 8 + j] = f2h(acc);
}

// W_hh fragment (24 nt x 4 kt)
__global__ void k_whh(const float* __restrict__ W_hh, u16* __restrict__ Wh16) {
  int c = blockIdx.x, k = threadIdx.x;
  float v = W_hh[(size_t)c * 128 + k];
  int nt = c >> 4, kt = k >> 5, g = (k & 31) >> 3, j = k & 7;
  int lane = (c & 15) + g * 16;
  Wh16[((size_t)nt * 4 + kt) * 512 + lane * 8 + j] = f2h(v);
}

__global__ void k_vbias(const float* __restrict__ W_ih, const float* __restrict__ bf2,
                        const float* __restrict__ br2, float* __restrict__ vf,
                        float* __restrict__ vr) {
  int c = blockIdx.x * blockDim.x + threadIdx.x;
  if (c >= 384) return;
  float a = 0.f, b = 0.f;
  for (int o = 0; o < 256; ++o) {
    float w = W_ih[(size_t)c * 256 + o];
    a = fmaf(w, bf2[o], a);
    b = fmaf(w, br2[o], b);
  }
  vf[c] = a; vr[c] = b;
}

// ns -> fp16 A-fragment (3125 mt x 4 kt)
__global__ void k_nsh(const float* __restrict__ ns, u16* __restrict__ nsf) {
  int t = blockIdx.x * 256 + threadIdx.x;
  int n = t >> 4, kk8 = t & 15;
  float4 v0 = *(const float4*)(ns + (size_t)n * 128 + kk8 * 8);
  float4 v1 = *(const float4*)(ns + (size_t)n * 128 + kk8 * 8 + 4);
  u16 hv[8] = {f2h(v0.x), f2h(v0.y), f2h(v0.z), f2h(v0.w),
               f2h(v1.x), f2h(v1.y), f2h(v1.z), f2h(v1.w)};
  int mt = n >> 4, r = n & 15, kt = kk8 >> 2, g = kk8 & 3;
  int lane = r + g * 16;
  *(uint4*)(nsf + ((size_t)mt * 4 + kt) * 512 + lane * 8) = *(const uint4*)hv;
}

// ---------------- CSR build ----------------
__global__ void k_hist(const int* __restrict__ from, const int* __restrict__ to,
                       int* __restrict__ cnt) {
  int e = blockIdx.x * 256 + threadIdx.x;
  if (e < NE) {
    atomicAdd(cnt + to[e], 1);
    atomicAdd(cnt + NN + from[e], 1);
  }
}

__global__ __launch_bounds__(256) void k_scanA(const int* __restrict__ cnt,
                                               int* __restrict__ bsum) {
  __shared__ int part[256];
  int b = blockIdx.x, tid = threadIdx.x;
  int idx = b * 1024 + tid * 4;
  int s = 0;
  if (idx + 3 < SCAN_N) {
    int4 v = *(const int4*)(cnt + idx);
    s = v.x + v.y + v.z + v.w;
  } else {
    for (int q = 0; q < 4; ++q)
      if (idx + q < SCAN_N) s += cnt[idx + q];
  }
  part[tid] = s;
  __syncthreads();
  for (int d = 128; d > 0; d >>= 1) {
    if (tid < d) part[tid] += part[tid + d];
    __syncthreads();
  }
  if (tid == 0) bsum[b] = part[0];
}

__global__ __launch_bounds__(128) void k_scanB(int* __restrict__ bsum) {
  __shared__ int part[128];
  int tid = threadIdx.x;
  int v = (tid < SCAN_BLOCKS) ? bsum[tid] : 0;
  part[tid] = v;
  __syncthreads();
  for (int d = 1; d < 128; d <<= 1) {
    int x = (tid >= d) ? part[tid - d] : 0;
    __syncthreads();
    part[tid] += x;
    __syncthreads();
  }
  if (tid < SCAN_BLOCKS) bsum[tid] = (tid > 0) ? part[tid - 1] : 0;
}

__global__ __launch_bounds__(256) void k_scanC(const int* __restrict__ cnt,
                                               const int* __restrict__ bsum,
                                               int* __restrict__ off,
                                               int* __restrict__ cur) {
  __shared__ int part[256];
  int b = blockIdx.x, tid = threadIdx.x;
  int idx = b * 1024 + tid * 4;
  int c[4] = {0, 0, 0, 0};
  if (idx + 3 < SCAN_N) {
    int4 v = *(const int4*)(cnt + idx);
    c[0] = v.x; c[1] = v.y; c[2] = v.z; c[3] = v.w;
  } else {
    for (int q = 0; q < 4; ++q)
      if (idx + q < SCAN_N) c[q] = cnt[idx + q];
  }
  int s = c[0] + c[1] + c[2] + c[3];
  part[tid] = s;
  __syncthreads();
  for (int d = 1; d < 256; d <<= 1) {
    int x = (tid >= d) ? part[tid - d] : 0;
    __syncthreads();
    part[tid] += x;
    __syncthreads();
  }
  int run = bsum[b] + ((tid > 0) ? part[tid - 1] : 0);
#pragma unroll
  for (int q = 0; q < 4; ++q) {
    if (idx + q < SCAN_N) {
      off[idx + q] = run;
      cur[idx + q] = run;
      run += c[q];
    }
  }
  if (b == 0 && tid == 0) off[SCAN_N] = 2 * NE;
}

__global__ void k_fill(const int* __restrict__ from, const int* __restrict__ to,
                       int* __restrict__ cur, int* __restrict__ nbr) {
  int e = blockIdx.x * 256 + threadIdx.x;
  if (e < NE) {
    int f = from[e], t = to[e];
    nbr[atomicAdd(cur + t, 1)] = f;
    nbr[atomicAdd(cur + NN + f, 1)] = t;
  }
}

// ---------------- K1: MFMA projection ----------------
__global__ __launch_bounds__(256) void k_proj(const u16* __restrict__ nsf,
                                              const u16* __restrict__ Wc16,
                                              const float* __restrict__ biascat,
                                              u16* __restrict__ T) {
  const int w = threadIdx.x >> 6, lane = threadIdx.x & 63;
  const int mt0 = blockIdx.x * 4;
  const int nt0 = blockIdx.y * 16 + w * 4;
  const h8 hzv = {(_Float16)0.f, (_Float16)0.f, (_Float16)0.f, (_Float16)0.f,
                  (_Float16)0.f, (_Float16)0.f, (_Float16)0.f, (_Float16)0.f};
  f4v acc[4][4];
#pragma unroll
  for (int m = 0; m < 4; ++m)
#pragma unroll
    for (int n = 0; n < 4; ++n) acc[m][n] = (f4v){0.f, 0.f, 0.f, 0.f};

#pragma unroll
  for (int kt = 0; kt < 4; ++kt) {
    h8 a[4], b[4];
#pragma unroll
    for (int m = 0; m < 4; ++m) {
      int mt = mt0 + m;
      a[m] = (mt < 3125) ? *(const h8*)(nsf + ((size_t)mt * 4 + kt) * 512 + lane * 8) : hzv;
    }
#pragma unroll
    for (int n = 0; n < 4; ++n)
      b[n] = *(const h8*)(Wc16 + ((size_t)(nt0 + n) * 4 + kt) * 512 + lane * 8);
#pragma unroll
    for (int m = 0; m < 4; ++m)
#pragma unroll
      for (int n = 0; n < 4; ++n)
        acc[m][n] = __builtin_amdgcn_mfma_f32_16x16x32_f16(a[m], b[n], acc[m][n], 0, 0, 0);
  }

  const int c0 = lane & 15, rB = (lane >> 4) * 4;
#pragma unroll
  for (int m = 0; m < 4; ++m) {
    int mt = mt0 + m;
    if (mt >= 3125) continue;
#pragma unroll
    for (int n = 0; n < 4; ++n) {
      int col = (nt0 + n) * 16 + c0;
      float bias = biascat[col];
#pragma unroll
      for (int reg = 0; reg < 4; ++reg) {
        int row = mt * 16 + rB + reg;
        T[(size_t)row * 1024 + col] = f2h(acc[m][n][reg] + bias);
      }
    }
  }
}

// ---------------- K2: CSR gather -> S in A-fragment layout (fp16) ----------------
// One wave per (node, dir). Packed-fp16 relu (pk_add/pk_max), fp32 accumulate,
// 8 neighbor loads in flight.
__global__ __launch_bounds__(256) void k_gather(const u16* __restrict__ T,
                                                const int* __restrict__ nbr,
                                                const int* __restrict__ off,
                                                u16* __restrict__ Sf) {
  const int lane = threadIdx.x & 63;
  const int gid = blockIdx.x * 4 + (threadIdx.x >> 6);
  const int n = gid >> 1, dir = gid & 1;
  const u16* Tn = T + (size_t)n * 1024;
  const int mt = n >> 4, r = n & 15;
  const int g = (lane & 7) >> 1, j0 = (lane & 1) * 4;
  const int laneF = r + g * 16;

  const int invofs = dir ? 256 : 512;
  const int gofs = dir ? 768 : 0;
  const h2 z2 = {(_Float16)0.f, (_Float16)0.f};
  h4 invv = *(const h4*)(Tn + invofs + lane * 4);
  h2 inv01 = {invv[0], invv[1]};
  h2 inv23 = {invv[2], invv[3]};
  const int s = off[dir * NN + n];
  const int e = off[dir * NN + n + 1];
  float a0 = 0.f, a1 = 0.f, a2 = 0.f, a3 = 0.f;

  for (int i = s; i < e; i += 64) {
    int nb = (i + lane < e) ? nbr[i + lane] : 0;
    int cnt = min(64, e - i);
    int k = 0;
    for (; k + 7 < cnt; k += 8) {
      h4 wv[8];
#pragma unroll
      for (int q = 0; q < 8; ++q) {
        int f = __shfl(nb, k + q);
        wv[q] = *(const h4*)(T + (size_t)f * 1024 + gofs + lane * 4);
      }
#pragma unroll
      for (int q = 0; q < 8; ++q) {
        h2 t01 = {wv[q][0], wv[q][1]};
        h2 t23 = {wv[q][2], wv[q][3]};
        t01 = __builtin_elementwise_max(t01 + inv01, z2);
        t23 = __builtin_elementwise_max(t23 + inv23, z2);
        a0 += (float)t01[0]; a1 += (float)t01[1];
        a2 += (float)t23[0]; a3 += (float)t23[1];
      }
    }
    if (k + 3 < cnt) {
      h4 wv[4];
#pragma unroll
      for (int q = 0; q < 4; ++q) {
        int f = __shfl(nb, k + q);
        wv[q] = *(const h4*)(T + (size_t)f * 1024 + gofs + lane * 4);
      }
#pragma unroll
      for (int q = 0; q < 4; ++q) {
        h2 t01 = {wv[q][0], wv[q][1]};
        h2 t23 = {wv[q][2], wv[q][3]};
        t01 = __builtin_elementwise_max(t01 + inv01, z2);
        t23 = __builtin_elementwise_max(t23 + inv23, z2);
        a0 += (float)t01[0]; a1 += (float)t01[1];
        a2 += (float)t23[0]; a3 += (float)t23[1];
      }
      k += 4;
    }
    for (; k < cnt; ++k) {
      int f = __shfl(nb, k);
      h4 wv = *(const h4*)(T + (size_t)f * 1024 + gofs + lane * 4);
      h2 t01 = {wv[0], wv[1]};
      h2 t23 = {wv[2], wv[3]};
      t01 = __builtin_elementwise_max(t01 + inv01, z2);
      t23 = __builtin_elementwise_max(t23 + inv23, z2);
      a0 += (float)t01[0]; a1 += (float)t01[1];
      a2 += (float)t23[0]; a3 += (float)t23[1];
    }
  }
  int kt = dir * 8 + (lane >> 3);
  u16 hv[4] = {f2h(a0), f2h(a1), f2h(a2), f2h(a3)};
  *(ushort4*)(Sf + ((size_t)mt * 16 + kt) * 512 + laneF * 8 + j0) = *(const ushort4*)hv;
}

// ---------------- K3: MFMA GRU, LDS-free, 2 mt + 3 nt per wave ----------------
// grid 3126: block b -> mt pair (b>>1)*2, half = b&1; wave w: base = half*4+w,
// nt(g) = base + 8g. B fragments loaded once, used for both mt.
__global__ __launch_bounds__(256) void k_gru(const u16* __restrict__ Sf,
                                             const u16* __restrict__ nsf,
                                             const u16* __restrict__ G16,
                                             const u16* __restrict__ Wh16,
                                             const float* __restrict__ ns,
                                             const float* __restrict__ b_ih,
                                             const float* __restrict__ b_hh,
                                             const float* __restrict__ vf,
                                             const float* __restrict__ vr,
                                             const int* __restrict__ off,
                                             float* __restrict__ out) {
  const int w = threadIdx.x >> 6, lane = threadIdx.x & 63;
  const int mt0 = (blockIdx.x >> 1) * 2, half = blockIdx.x & 1;
  const int base = half * 4 + w;
  const bool has1 = (mt0 + 1) < 3125;
  const h8 hz = {(_Float16)0.f, (_Float16)0.f, (_Float16)0.f, (_Float16)0.f,
                 (_Float16)0.f, (_Float16)0.f, (_Float16)0.f, (_Float16)0.f};

  f4v gh[2][3], gi[2][3];
#pragma unroll
  for (int m = 0; m < 2; ++m)
#pragma unroll
    for (int g = 0; g < 3; ++g) {
      gh[m][g] = (f4v){0.f, 0.f, 0.f, 0.f};
      gi[m][g] = (f4v){0.f, 0.f, 0.f, 0.f};
    }

  // step A: gh = ns @ W_hh.T (K=128)
#pragma unroll
  for (int kt = 0; kt < 4; ++kt) {
    h8 a0 = *(const h8*)(nsf + ((size_t)mt0 * 4 + kt) * 512 + lane * 8);
    h8 a1 = has1 ? *(const h8*)(nsf + ((size_t)(mt0 + 1) * 4 + kt) * 512 + lane * 8) : hz;
#pragma unroll
    for (int g = 0; g < 3; ++g) {
      h8 b = *(const h8*)(Wh16 + ((size_t)(base + 8 * g) * 4 + kt) * 512 + lane * 8);
      gh[0][g] = __builtin_amdgcn_mfma_f32_16x16x32_f16(a0, b, gh[0][g], 0, 0, 0);
      gh[1][g] = __builtin_amdgcn_mfma_f32_16x16x32_f16(a1, b, gh[1][g], 0, 0, 0);
    }
  }

  // step B: gi = S @ Gcat.T (K=512)
#pragma unroll
  for (int kt = 0; kt < 16; ++kt) {
    h8 a0 = *(const h8*)(Sf + ((size_t)mt0 * 16 + kt) * 512 + lane * 8);
    h8 a1 = has1 ? *(const h8*)(Sf + ((size_t)(mt0 + 1) * 16 + kt) * 512 + lane * 8) : hz;
#pragma unroll
    for (int g = 0; g < 3; ++g) {
      h8 b = *(const h8*)(G16 + ((size_t)(base + 8 * g) * 16 + kt) * 512 + lane * 8);
      gi[0][g] = __builtin_amdgcn_mfma_f32_16x16x32_f16(a0, b, gi[0][g], 0, 0, 0);
      gi[1][g] = __builtin_amdgcn_mfma_f32_16x16x32_f16(a1, b, gi[1][g], 0, 0, 0);
    }
  }

  // epilogue
  const int c0 = lane & 15, rB = (lane >> 4) * 4;
  const int d = base * 16 + c0;
  const float vf0 = vf[d], vf1 = vf[128 + d], vf2 = vf[256 + d];
  const float vr0 = vr[d], vr1 = vr[128 + d], vr2 = vr[256 + d];
  const float bi0 = b_ih[d], bi1 = b_ih[128 + d], bi2 = b_ih[256 + d];
  const float bh0 = b_hh[d], bh1 = b_hh[128 + d], bh2 = b_hh[256 + d];
#pragma unroll
  for (int m = 0; m < 2; ++m) {
    if (m == 1 && !has1) continue;
    const int mt = mt0 + m;
#pragma unroll
    for (int reg = 0; reg < 4; ++reg) {
      int row = mt * 16 + rB + reg;
      float idg = (float)(off[row + 1] - off[row]);
      float odg = (float)(off[NN + row + 1] - off[NN + row]);
      float gr = gi[m][0][reg] + idg * vf0 + odg * vr0 + bi0;
      float gz = gi[m][1][reg] + idg * vf1 + odg * vr1 + bi1;
      float gn = gi[m][2][reg] + idg * vf2 + odg * vr2 + bi2;
      float hr = gh[m][0][reg] + bh0;
      float hzv = gh[m][1][reg] + bh1;
      float hn = gh[m][2][reg] + bh2;
      float rg = 1.f / (1.f + __expf(-(gr + hr)));
      float zg = 1.f / (1.f + __expf(-(gz + hzv)));
      float ng = tanhf(gn + rg * hn);
      float h = ns[(size_t)row * 128 + d];
      out[(size_t)row * 128 + d] = (1.f - zg) * ng + zg * h;
    }
  }
}

// ---------------- launch ----------------
extern "C" void kernel_launch(void* const* d_in, const int* in_sizes, int n_in,
                              void* d_out, int out_size, void* d_ws, size_t ws_size,
                              hipStream_t stream) {
  const float* ns   = (const float*)d_in[0];
  const int* from   = (const int*)d_in[1];
  const int* to     = (const int*)d_in[2];
  const float* Wf1  = (const float*)d_in[3];
  const float* bf1  = (const float*)d_in[4];
  const float* Wf2  = (const float*)d_in[5];
  const float* bf2  = (const float*)d_in[6];
  const float* Wr1  = (const float*)d_in[7];
  const float* br1  = (const float*)d_in[8];
  const float* Wr2  = (const float*)d_in[9];
  const float* br2  = (const float*)d_in[10];
  const float* W_ih = (const float*)d_in[11];
  const float* W_hh = (const float*)d_in[12];
  const float* b_ih = (const float*)d_in[13];
  const float* b_hh = (const float*)d_in[14];
  float* out = (float*)d_out;

  // workspace layout (256B aligned)
  char* w = (char*)d_ws;
  u16*   Wc16    = (u16*)(w + 0);            // 262144
  float* biascat = (float*)(w + 262144);     // 4096
  u16*   G16     = (u16*)(w + 266240);       // 393216
  u16*   Wh16    = (u16*)(w + 659456);       // 98304
  float* vf      = (float*)(w + 757760);     // 1536
  float* vr      = (float*)(w + 759296);     // 1536
  int*   cnt     = (int*)(w + 760832);       // 400128
  int*   off     = (int*)(w + 1160960);      // 400128
  int*   cur     = (int*)(w + 1561088);      // 400128
  int*   bsum    = (int*)(w + 1961216);      // 512
  int*   nbr     = (int*)(w + 1961728);      // 4096000
  u16*   nsf     = (u16*)(w + 6057728);      // 12800000
  u16*   T       = (u16*)(w + 18857728);     // 102400000
  u16*   Sf      = (u16*)(w + 121257728);    // 51200000
  // total 172457728 bytes

  hipMemsetAsync(cnt, 0, 400000, stream);

  k_wcat<<<1024, 128, 0, stream>>>(Wf1, bf1, Wr1, br1, Wc16, biascat);
  k_gcat<<<768, 256, 0, stream>>>(W_ih, Wf2, Wr2, G16);
  k_whh<<<384, 128, 0, stream>>>(W_hh, Wh16);
  k_vbias<<<3, 128, 0, stream>>>(W_ih, bf2, br2, vf, vr);
  k_nsh<<<3125, 256, 0, stream>>>(ns, nsf);

  k_hist<<<(NE + 255) / 256, 256, 0, stream>>>(from, to, cnt);
  k_scanA<<<SCAN_BLOCKS, 256, 0, stream>>>(cnt, bsum);
  k_scanB<<<1, 128, 0, stream>>>(bsum);
  k_scanC<<<SCAN_BLOCKS, 256, 0, stream>>>(cnt, bsum, off, cur);
  k_fill<<<(NE + 255) / 256, 256, 0, stream>>>(from, to, cur, nbr);

  k_proj<<<dim3(782, 4), 256, 0, stream>>>(nsf, Wc16, biascat, T);
  k_gather<<<25000, 256, 0, stream>>>(T, nbr, off, Sf);
  k_gru<<<3126, 256, 0, stream>>>(Sf, nsf, G16, Wh16, ns, b_ih, b_hh, vf, vr, off, out);
}

// Round 8
// 348.199 us; speedup vs baseline: 12.7016x; 1.0013x over previous
//
#include <hip/hip_runtime.h>
#include <stdint.h>

// GraphPropLayer on MI355X — round 8: split T into Tin/Tout/Tnode dense tables
// (kills cache set-conflicts from 2KB-stride slices), direction-grouped gather.
//
// Fragment layout (v_mfma_f32_16x16x32_f16):
//   A (16m x 32k): lane = row + 16*((k%32)/8), elem j = k%8
//   B (32k x 16n): lane = col + 16*((k%32)/8), elem j = k%8
//   C/D: col = lane&15, row = (lane>>4)*4 + reg
// Tile = 512 halfs (1 KB); buffers indexed [(mt_or_nt * KT + kt)*512 + lane*8 + j].

#define NN 50000
#define NE 512000
#define SCAN_N (2 * NN)
#define SCAN_BLOCKS ((SCAN_N + 1023) / 1024)  // 98

typedef unsigned short u16;
typedef unsigned int u32;
using h2  = __attribute__((ext_vector_type(2))) _Float16;
using h4  = __attribute__((ext_vector_type(4))) _Float16;
using h8  = __attribute__((ext_vector_type(8))) _Float16;
using f4v = __attribute__((ext_vector_type(4))) float;

__device__ __forceinline__ float h2f(u16 u) {
  _Float16 h; __builtin_memcpy(&h, &u, 2); return (float)h;
}
__device__ __forceinline__ u16 f2h(float f) {
  _Float16 h = (_Float16)f; u16 u; __builtin_memcpy(&u, &h, 2); return u;
}

// ---------------- prep kernels (tiny) ----------------

// Wcat fragment (64 nt x 4 kt). Logical col c semantics:
// [0,256): Wf1[:,0:128](+bf1)   -> Tin   (random-read, in-gather)
// [256,512): Wr1[:,128:256]     -> Tnode[0:256)   (rev self)
// [512,768): Wf1[:,128:256]     -> Tnode[256:512) (fwd self)
// [768,1024): Wr1[:,0:128](+br1)-> Tout  (random-read, out-gather)
__global__ void k_wcat(const float* __restrict__ Wf1, const float* __restrict__ bf1,
                       const float* __restrict__ Wr1, const float* __restrict__ br1,
                       u16* __restrict__ Wc16, float* __restrict__ biascat) {
  int c = blockIdx.x;
  int k = threadIdx.x;
  const float* src;
  if (c < 256)      src = Wf1 + (size_t)c * 256;
  else if (c < 512) src = Wr1 + (size_t)(c - 256) * 256 + 128;
  else if (c < 768) src = Wf1 + (size_t)(c - 512) * 256 + 128;
  else              src = Wr1 + (size_t)(c - 768) * 256;
  float v = src[k];
  int nt = c >> 4, kt = k >> 5, g = (k & 31) >> 3, j = k & 7;
  int lane = (c & 15) + g * 16;
  Wc16[((size_t)nt * 4 + kt) * 512 + lane * 8 + j] = f2h(v);
  if (k == 0) biascat[c] = (c < 256) ? bf1[c] : ((c >= 768) ? br1[c - 768] : 0.f);
}

// Gcat fragment (24 nt x 16 kt)
__global__ void k_gcat(const float* __restrict__ W_ih, const float* __restrict__ Wf2,
                       const float* __restrict__ Wr2, u16* __restrict__ G16) {
  int b = blockIdx.x;
  int c = b % 384, w = b / 384;
  const float* W2 = w ? Wr2 : Wf2;
  int k = threadIdx.x;
  float acc = 0.f;
  for (int o = 0; o < 256; ++o)
    acc = fmaf(W_ih[(size_t)c * 256 + o], W2[(size_t)o * 256 + k], acc);
  int kg = w * 256 + k;
  int nt = c >> 4, kt = kg >> 5, g = (kg & 31) >> 3, j = kg & 7;
  int lane = (c & 15) + g * 16;
  G16[((size_t)nt * 16 + kt) * 512 + lane * 8 + j] = f2h(acc);
}

// W_hh fragment (24 nt x 4 kt)
__global__ void k_whh(const float* __restrict__ W_hh, u16* __restrict__ Wh16) {
  int c = blockIdx.x, k = threadIdx.x;
  float v = W_hh[(size_t)c * 128 + k];
  int nt = c >> 4, kt = k >> 5, g = (k & 31) >> 3, j = k & 7;
  int lane = (c & 15) + g * 16;
  Wh16[((size_t)nt * 4 + kt) * 512 + lane * 8 + j] = f2h(v);
}

__global__ void k_vbias(const float* __restrict__ W_ih, const float* __restrict__ bf2,
                        const float* __restrict__ br2, float* __restrict__ vf,
                        float* __restrict__ vr) {
  int c = blockIdx.x * blockDim.x + threadIdx.x;
  if (c >= 384) return;
  float a = 0.f, b = 0.f;
  for (int o = 0; o < 256; ++o) {
    float w = W_ih[(size_t)c * 256 + o];
    a = fmaf(w, bf2[o], a);
    b = fmaf(w, br2[o], b);
  }
  vf[c] = a; vr[c] = b;
}

// ns -> fp16 A-fragment (3125 mt x 4 kt)
__global__ void k_nsh(const float* __restrict__ ns, u16* __restrict__ nsf) {
  int t = blockIdx.x * 256 + threadIdx.x;
  int n = t >> 4, kk8 = t & 15;
  float4 v0 = *(const float4*)(ns + (size_t)n * 128 + kk8 * 8);
  float4 v1 = *(const float4*)(ns + (size_t)n * 128 + kk8 * 8 + 4);
  u16 hv[8] = {f2h(v0.x), f2h(v0.y), f2h(v0.z), f2h(v0.w),
               f2h(v1.x), f2h(v1.y), f2h(v1.z), f2h(v1.w)};
  int mt = n >> 4, r = n & 15, kt = kk8 >> 2, g = kk8 & 3;
  int lane = r + g * 16;
  *(uint4*)(nsf + ((size_t)mt * 4 + kt) * 512 + lane * 8) = *(const uint4*)hv;
}

// ---------------- CSR build ----------------
__global__ void k_hist(const int* __restrict__ from, const int* __restrict__ to,
                       int* __restrict__ cnt) {
  int e = blockIdx.x * 256 + threadIdx.x;
  if (e < NE) {
    atomicAdd(cnt + to[e], 1);
    atomicAdd(cnt + NN + from[e], 1);
  }
}

__global__ __launch_bounds__(256) void k_scanA(const int* __restrict__ cnt,
                                               int* __restrict__ bsum) {
  __shared__ int part[256];
  int b = blockIdx.x, tid = threadIdx.x;
  int idx = b * 1024 + tid * 4;
  int s = 0;
  if (idx + 3 < SCAN_N) {
    int4 v = *(const int4*)(cnt + idx);
    s = v.x + v.y + v.z + v.w;
  } else {
    for (int q = 0; q < 4; ++q)
      if (idx + q < SCAN_N) s += cnt[idx + q];
  }
  part[tid] = s;
  __syncthreads();
  for (int d = 128; d > 0; d >>= 1) {
    if (tid < d) part[tid] += part[tid + d];
    __syncthreads();
  }
  if (tid == 0) bsum[b] = part[0];
}

__global__ __launch_bounds__(128) void k_scanB(int* __restrict__ bsum) {
  __shared__ int part[128];
  int tid = threadIdx.x;
  int v = (tid < SCAN_BLOCKS) ? bsum[tid] : 0;
  part[tid] = v;
  __syncthreads();
  for (int d = 1; d < 128; d <<= 1) {
    int x = (tid >= d) ? part[tid - d] : 0;
    __syncthreads();
    part[tid] += x;
    __syncthreads();
  }
  if (tid < SCAN_BLOCKS) bsum[tid] = (tid > 0) ? part[tid - 1] : 0;
}

__global__ __launch_bounds__(256) void k_scanC(const int* __restrict__ cnt,
                                               const int* __restrict__ bsum,
                                               int* __restrict__ off,
                                               int* __restrict__ cur) {
  __shared__ int part[256];
  int b = blockIdx.x, tid = threadIdx.x;
  int idx = b * 1024 + tid * 4;
  int c[4] = {0, 0, 0, 0};
  if (idx + 3 < SCAN_N) {
    int4 v = *(const int4*)(cnt + idx);
    c[0] = v.x; c[1] = v.y; c[2] = v.z; c[3] = v.w;
  } else {
    for (int q = 0; q < 4; ++q)
      if (idx + q < SCAN_N) c[q] = cnt[idx + q];
  }
  int s = c[0] + c[1] + c[2] + c[3];
  part[tid] = s;
  __syncthreads();
  for (int d = 1; d < 256; d <<= 1) {
    int x = (tid >= d) ? part[tid - d] : 0;
    __syncthreads();
    part[tid] += x;
    __syncthreads();
  }
  int run = bsum[b] + ((tid > 0) ? part[tid - 1] : 0);
#pragma unroll
  for (int q = 0; q < 4; ++q) {
    if (idx + q < SCAN_N) {
      off[idx + q] = run;
      cur[idx + q] = run;
      run += c[q];
    }
  }
  if (b == 0 && tid == 0) off[SCAN_N] = 2 * NE;
}

__global__ void k_fill(const int* __restrict__ from, const int* __restrict__ to,
                       int* __restrict__ cur, int* __restrict__ nbr) {
  int e = blockIdx.x * 256 + threadIdx.x;
  if (e < NE) {
    int f = from[e], t = to[e];
    nbr[atomicAdd(cur + t, 1)] = f;
    nbr[atomicAdd(cur + NN + f, 1)] = t;
  }
}

// ---------------- K1: MFMA projection -> Tin / Tnode / Tout ----------------
__global__ __launch_bounds__(256) void k_proj(const u16* __restrict__ nsf,
                                              const u16* __restrict__ Wc16,
                                              const float* __restrict__ biascat,
                                              u16* __restrict__ Tin,
                                              u16* __restrict__ Tnode,
                                              u16* __restrict__ Tout) {
  const int w = threadIdx.x >> 6, lane = threadIdx.x & 63;
  const int mt0 = blockIdx.x * 4;
  const int nt0 = blockIdx.y * 16 + w * 4;
  const h8 hzv = {(_Float16)0.f, (_Float16)0.f, (_Float16)0.f, (_Float16)0.f,
                  (_Float16)0.f, (_Float16)0.f, (_Float16)0.f, (_Float16)0.f};
  f4v acc[4][4];
#pragma unroll
  for (int m = 0; m < 4; ++m)
#pragma unroll
    for (int n = 0; n < 4; ++n) acc[m][n] = (f4v){0.f, 0.f, 0.f, 0.f};

#pragma unroll
  for (int kt = 0; kt < 4; ++kt) {
    h8 a[4], b[4];
#pragma unroll
    for (int m = 0; m < 4; ++m) {
      int mt = mt0 + m;
      a[m] = (mt < 3125) ? *(const h8*)(nsf + ((size_t)mt * 4 + kt) * 512 + lane * 8) : hzv;
    }
#pragma unroll
    for (int n = 0; n < 4; ++n)
      b[n] = *(const h8*)(Wc16 + ((size_t)(nt0 + n) * 4 + kt) * 512 + lane * 8);
#pragma unroll
    for (int m = 0; m < 4; ++m)
#pragma unroll
      for (int n = 0; n < 4; ++n)
        acc[m][n] = __builtin_amdgcn_mfma_f32_16x16x32_f16(a[m], b[n], acc[m][n], 0, 0, 0);
  }

  const int c0 = lane & 15, rB = (lane >> 4) * 4;
#pragma unroll
  for (int n = 0; n < 4; ++n) {
    const int ntg = nt0 + n;
    u16* dst;
    size_t stride;
    int col;
    if (ntg < 16)      { dst = Tin;   stride = 256; col = ntg * 16 + c0; }
    else if (ntg < 48) { dst = Tnode; stride = 512; col = (ntg - 16) * 16 + c0; }
    else               { dst = Tout;  stride = 256; col = (ntg - 48) * 16 + c0; }
    float bias = biascat[ntg * 16 + c0];
#pragma unroll
    for (int m = 0; m < 4; ++m) {
      int mt = mt0 + m;
      if (mt >= 3125) continue;
#pragma unroll
      for (int reg = 0; reg < 4; ++reg) {
        int row = mt * 16 + rB + reg;
        dst[(size_t)row * stride + col] = f2h(acc[m][n][reg] + bias);
      }
    }
  }
}

// ---------------- K2: CSR gather -> S in A-fragment layout (fp16) ----------------
// One wave per (node, dir); all dir0 waves first (L3 working set = one table).
// dir0: S[n][0:256) = sum_f relu(Tnode[n][256+c] + Tin[f][c])
// dir1: S[n][256:512) = sum_t relu(Tnode[n][c] + Tout[t][c])
__global__ __launch_bounds__(256) void k_gather(const u16* __restrict__ Tin,
                                                const u16* __restrict__ Tnode,
                                                const u16* __restrict__ Tout,
                                                const int* __restrict__ nbr,
                                                const int* __restrict__ off,
                                                u16* __restrict__ Sf) {
  const int lane = threadIdx.x & 63;
  const int gid = blockIdx.x * 4 + (threadIdx.x >> 6);
  const int dir = (gid >= NN) ? 1 : 0;
  const int n = gid - dir * NN;
  const int mt = n >> 4, r = n & 15;
  const int g = (lane & 7) >> 1, j0 = (lane & 1) * 4;
  const int laneF = r + g * 16;

  const u16* gtab = dir ? Tout : Tin;
  const int invofs = dir ? 0 : 256;
  const h2 z2 = {(_Float16)0.f, (_Float16)0.f};
  h4 invv = *(const h4*)(Tnode + (size_t)n * 512 + invofs + lane * 4);
  h2 inv01 = {invv[0], invv[1]};
  h2 inv23 = {invv[2], invv[3]};
  const int s = off[dir * NN + n];
  const int e = off[dir * NN + n + 1];
  float a0 = 0.f, a1 = 0.f, a2 = 0.f, a3 = 0.f;

  for (int i = s; i < e; i += 64) {
    int nb = (i + lane < e) ? nbr[i + lane] : 0;
    int cnt = min(64, e - i);
    int k = 0;
    for (; k + 7 < cnt; k += 8) {
      h4 wv[8];
#pragma unroll
      for (int q = 0; q < 8; ++q) {
        int f = __shfl(nb, k + q);
        wv[q] = *(const h4*)(gtab + (size_t)f * 256 + lane * 4);
      }
#pragma unroll
      for (int q = 0; q < 8; ++q) {
        h2 t01 = {wv[q][0], wv[q][1]};
        h2 t23 = {wv[q][2], wv[q][3]};
        t01 = __builtin_elementwise_max(t01 + inv01, z2);
        t23 = __builtin_elementwise_max(t23 + inv23, z2);
        a0 += (float)t01[0]; a1 += (float)t01[1];
        a2 += (float)t23[0]; a3 += (float)t23[1];
      }
    }
    if (k + 3 < cnt) {
      h4 wv[4];
#pragma unroll
      for (int q = 0; q < 4; ++q) {
        int f = __shfl(nb, k + q);
        wv[q] = *(const h4*)(gtab + (size_t)f * 256 + lane * 4);
      }
#pragma unroll
      for (int q = 0; q < 4; ++q) {
        h2 t01 = {wv[q][0], wv[q][1]};
        h2 t23 = {wv[q][2], wv[q][3]};
        t01 = __builtin_elementwise_max(t01 + inv01, z2);
        t23 = __builtin_elementwise_max(t23 + inv23, z2);
        a0 += (float)t01[0]; a1 += (float)t01[1];
        a2 += (float)t23[0]; a3 += (float)t23[1];
      }
      k += 4;
    }
    for (; k < cnt; ++k) {
      int f = __shfl(nb, k);
      h4 wv = *(const h4*)(gtab + (size_t)f * 256 + lane * 4);
      h2 t01 = {wv[0], wv[1]};
      h2 t23 = {wv[2], wv[3]};
      t01 = __builtin_elementwise_max(t01 + inv01, z2);
      t23 = __builtin_elementwise_max(t23 + inv23, z2);
      a0 += (float)t01[0]; a1 += (float)t01[1];
      a2 += (float)t23[0]; a3 += (float)t23[1];
    }
  }
  int kt = dir * 8 + (lane >> 3);
  u16 hv[4] = {f2h(a0), f2h(a1), f2h(a2), f2h(a3)};
  *(ushort4*)(Sf + ((size_t)mt * 16 + kt) * 512 + laneF * 8 + j0) = *(const ushort4*)hv;
}

// ---------------- K3: MFMA GRU, LDS-free, 2 mt + 3 nt per wave ----------------
__global__ __launch_bounds__(256) void k_gru(const u16* __restrict__ Sf,
                                             const u16* __restrict__ nsf,
                                             const u16* __restrict__ G16,
                                             const u16* __restrict__ Wh16,
                                             const float* __restrict__ ns,
                                             const float* __restrict__ b_ih,
                                             const float* __restrict__ b_hh,
                                             const float* __restrict__ vf,
                                             const float* __restrict__ vr,
                                             const int* __restrict__ off,
                                             float* __restrict__ out) {
  const int w = threadIdx.x >> 6, lane = threadIdx.x & 63;
  const int mt0 = (blockIdx.x >> 1) * 2, half = blockIdx.x & 1;
  const int base = half * 4 + w;
  const bool has1 = (mt0 + 1) < 3125;
  const h8 hz = {(_Float16)0.f, (_Float16)0.f, (_Float16)0.f, (_Float16)0.f,
                 (_Float16)0.f, (_Float16)0.f, (_Float16)0.f, (_Float16)0.f};

  f4v gh[2][3], gi[2][3];
#pragma unroll
  for (int m = 0; m < 2; ++m)
#pragma unroll
    for (int g = 0; g < 3; ++g) {
      gh[m][g] = (f4v){0.f, 0.f, 0.f, 0.f};
      gi[m][g] = (f4v){0.f, 0.f, 0.f, 0.f};
    }

  // step A: gh = ns @ W_hh.T (K=128)
#pragma unroll
  for (int kt = 0; kt < 4; ++kt) {
    h8 a0 = *(const h8*)(nsf + ((size_t)mt0 * 4 + kt) * 512 + lane * 8);
    h8 a1 = has1 ? *(const h8*)(nsf + ((size_t)(mt0 + 1) * 4 + kt) * 512 + lane * 8) : hz;
#pragma unroll
    for (int g = 0; g < 3; ++g) {
      h8 b = *(const h8*)(Wh16 + ((size_t)(base + 8 * g) * 4 + kt) * 512 + lane * 8);
      gh[0][g] = __builtin_amdgcn_mfma_f32_16x16x32_f16(a0, b, gh[0][g], 0, 0, 0);
      gh[1][g] = __builtin_amdgcn_mfma_f32_16x16x32_f16(a1, b, gh[1][g], 0, 0, 0);
    }
  }

  // step B: gi = S @ Gcat.T (K=512)
#pragma unroll
  for (int kt = 0; kt < 16; ++kt) {
    h8 a0 = *(const h8*)(Sf + ((size_t)mt0 * 16 + kt) * 512 + lane * 8);
    h8 a1 = has1 ? *(const h8*)(Sf + ((size_t)(mt0 + 1) * 16 + kt) * 512 + lane * 8) : hz;
#pragma unroll
    for (int g = 0; g < 3; ++g) {
      h8 b = *(const h8*)(G16 + ((size_t)(base + 8 * g) * 16 + kt) * 512 + lane * 8);
      gi[0][g] = __builtin_amdgcn_mfma_f32_16x16x32_f16(a0, b, gi[0][g], 0, 0, 0);
      gi[1][g] = __builtin_amdgcn_mfma_f32_16x16x32_f16(a1, b, gi[1][g], 0, 0, 0);
    }
  }

  // epilogue
  const int c0 = lane & 15, rB = (lane >> 4) * 4;
  const int d = base * 16 + c0;
  const float vf0 = vf[d], vf1 = vf[128 + d], vf2 = vf[256 + d];
  const float vr0 = vr[d], vr1 = vr[128 + d], vr2 = vr[256 + d];
  const float bi0 = b_ih[d], bi1 = b_ih[128 + d], bi2 = b_ih[256 + d];
  const float bh0 = b_hh[d], bh1 = b_hh[128 + d], bh2 = b_hh[256 + d];
#pragma unroll
  for (int m = 0; m < 2; ++m) {
    if (m == 1 && !has1) continue;
    const int mt = mt0 + m;
#pragma unroll
    for (int reg = 0; reg < 4; ++reg) {
      int row = mt * 16 + rB + reg;
      float idg = (float)(off[row + 1] - off[row]);
      float odg = (float)(off[NN + row + 1] - off[NN + row]);
      float gr = gi[m][0][reg] + idg * vf0 + odg * vr0 + bi0;
      float gz = gi[m][1][reg] + idg * vf1 + odg * vr1 + bi1;
      float gn = gi[m][2][reg] + idg * vf2 + odg * vr2 + bi2;
      float hr = gh[m][0][reg] + bh0;
      float hzv = gh[m][1][reg] + bh1;
      float hn = gh[m][2][reg] + bh2;
      float rg = 1.f / (1.f + __expf(-(gr + hr)));
      float zg = 1.f / (1.f + __expf(-(gz + hzv)));
      float ng = tanhf(gn + rg * hn);
      float h = ns[(size_t)row * 128 + d];
      out[(size_t)row * 128 + d] = (1.f - zg) * ng + zg * h;
    }
  }
}

// ---------------- launch ----------------
extern "C" void kernel_launch(void* const* d_in, const int* in_sizes, int n_in,
                              void* d_out, int out_size, void* d_ws, size_t ws_size,
                              hipStream_t stream) {
  const float* ns   = (const float*)d_in[0];
  const int* from   = (const int*)d_in[1];
  const int* to     = (const int*)d_in[2];
  const float* Wf1  = (const float*)d_in[3];
  const float* bf1  = (const float*)d_in[4];
  const float* Wf2  = (const float*)d_in[5];
  const float* bf2  = (const float*)d_in[6];
  const float* Wr1  = (const float*)d_in[7];
  const float* br1  = (const float*)d_in[8];
  const float* Wr2  = (const float*)d_in[9];
  const float* br2  = (const float*)d_in[10];
  const float* W_ih = (const float*)d_in[11];
  const float* W_hh = (const float*)d_in[12];
  const float* b_ih = (const float*)d_in[13];
  const float* b_hh = (const float*)d_in[14];
  float* out = (float*)d_out;

  // workspace layout (256B aligned)
  char* w = (char*)d_ws;
  u16*   Wc16    = (u16*)(w + 0);            // 262144
  float* biascat = (float*)(w + 262144);     // 4096
  u16*   G16     = (u16*)(w + 266240);       // 393216
  u16*   Wh16    = (u16*)(w + 659456);       // 98304
  float* vf      = (float*)(w + 757760);     // 1536
  float* vr      = (float*)(w + 759296);     // 1536
  int*   cnt     = (int*)(w + 760832);       // 400128
  int*   off     = (int*)(w + 1160960);      // 400128
  int*   cur     = (int*)(w + 1561088);      // 400128
  int*   bsum    = (int*)(w + 1961216);      // 512
  int*   nbr     = (int*)(w + 1961728);      // 4096000
  u16*   nsf     = (u16*)(w + 6057728);      // 12800000
  u16*   Tin     = (u16*)(w + 18857728);     // 50000*256*2 = 25600000
  u16*   Tout    = (u16*)(w + 44457728);     // 25600000
  u16*   Tnode   = (u16*)(w + 70057728);     // 50000*512*2 = 51200000
  u16*   Sf      = (u16*)(w + 121257728);    // 51200000
  // total 172457728 bytes

  hipMemsetAsync(cnt, 0, 400000, stream);

  k_wcat<<<1024, 128, 0, stream>>>(Wf1, bf1, Wr1, br1, Wc16, biascat);
  k_gcat<<<768, 256, 0, stream>>>(W_ih, Wf2, Wr2, G16);
  k_whh<<<384, 128, 0, stream>>>(W_hh, Wh16);
  k_vbias<<<3, 128, 0, stream>>>(W_ih, bf2, br2, vf, vr);
  k_nsh<<<3125, 256, 0, stream>>>(ns, nsf);

  k_hist<<<(NE + 255) / 256, 256, 0, stream>>>(from, to, cnt);
  k_scanA<<<SCAN_BLOCKS, 256, 0, stream>>>(cnt, bsum);
  k_scanB<<<1, 128, 0, stream>>>(bsum);
  k_scanC<<<SCAN_BLOCKS, 256, 0, stream>>>(cnt, bsum, off, cur);
  k_fill<<<(NE + 255) / 256, 256, 0, stream>>>(from, to, cur, nbr);

  k_proj<<<dim3(782, 4), 256, 0, stream>>>(nsf, Wc16, biascat, Tin, Tnode, Tout);
  k_gather<<<25000, 256, 0, stream>>>(Tin, Tnode, Tout, nbr, off, Sf);
  k_gru<<<3126, 256, 0, stream>>>(Sf, nsf, G16, Wh16, ns, b_ih, b_hh, vf, vr, off, out);
}